// Round 13
// baseline (638.519 us; speedup 1.0000x reference)
//
#include <hip/hip_runtime.h>
#include <hip/hip_bf16.h>

#define BB 64
#define SS 512
#define II 32
#define HH 64
#define DD 128
#define FF 256
#define NHEAD 8
#define HDIM 16
#define NTOK (SS*BB)   // 32768

typedef short bf16x8 __attribute__((ext_vector_type(8)));
typedef float f32x4  __attribute__((ext_vector_type(4)));

__device__ __forceinline__ float fast_tanh(float x) {
    float ax = fabsf(x);
    float e = __expf(-2.0f * ax);
    float r = (1.0f - e) * __builtin_amdgcn_rcpf(1.0f + e);
    return copysignf(r, x);
}

__device__ __forceinline__ float bcast(float v, int lane) {
    return __int_as_float(__builtin_amdgcn_readlane(__float_as_int(v), lane));
}

__device__ __forceinline__ short f2bf(float x) {
    unsigned u = __float_as_uint(x);
    return (short)((u + 0x7FFFu + ((u >> 16) & 1u)) >> 16);
}

// device-scope grid barrier: counters zeroed by hipMemsetAsync before launch.
// release-add / acquire-load at agent scope (acquire emits L1 invalidate --
// required for ws regions reused across phases; G16).
__device__ __forceinline__ void gbar(unsigned* c, unsigned nblk) {
    __syncthreads();
    if (threadIdx.x == 0) {
        __hip_atomic_fetch_add(c, 1u, __ATOMIC_ACQ_REL, __HIP_MEMORY_SCOPE_AGENT);
        while (__hip_atomic_load(c, __ATOMIC_ACQUIRE, __HIP_MEMORY_SCOPE_AGENT) < nblk)
            __builtin_amdgcn_s_sleep(2);
        __threadfence();
    }
    __syncthreads();
}

// ---------------- Kernel 1: xw = x @ W_ih^T + b_ih + b_hh, layout (S,B,H) ----
__global__ __launch_bounds__(256) void k_xw(const float* __restrict__ x,
                                            const float* __restrict__ W_ih,
                                            const float* __restrict__ b_ih,
                                            const float* __restrict__ b_hh,
                                            float* __restrict__ xw) {
    int idx = blockIdx.x * 256 + threadIdx.x;  // over S*B*H = 2M
    int j  = idx & (HH - 1);
    int sb = idx >> 6;          // s*B + b
    int s  = sb >> 6;           // / B
    int b  = sb & (BB - 1);
    const float* xr = x + (b * SS + s) * II;
    const float* wr = W_ih + j * II;
    float acc = b_ih[j] + b_hh[j];
    #pragma unroll
    for (int k = 0; k < II; k += 4) {
        float4 xv = *(const float4*)(xr + k);
        float4 wv = *(const float4*)(wr + k);
        acc += xv.x * wv.x + xv.y * wv.y + xv.z * wv.z + xv.w * wv.w;
    }
    xw[idx] = acc;
}

// ---------------- Kernel 2: RNN recurrence, one block (1 wave) per batch ----
// FROZEN: byte-for-byte the R4/R5 body -- measured 134.5us FOUR times.
// Six variants all lost. DO NOT TOUCH without a structural idea.
__global__ __launch_bounds__(64, 1) void k_rnn(const float* __restrict__ xw,
                                               const float* __restrict__ W_hh,
                                               float* __restrict__ hs) {
    int b = blockIdx.x;
    int j = threadIdx.x;
    float w[HH];
    #pragma unroll
    for (int k = 0; k < HH; k++) w[k] = W_hh[j * HH + k];

    float hv = 0.0f;
    float xv0 = xw[(0 * BB + b) * HH + j];
    float xv1 = xw[(1 * BB + b) * HH + j];
    for (int t = 0; t < SS; t++) {
        int tn = (t < SS - 2) ? t + 2 : t;
        float xnext = xw[(tn * BB + b) * HH + j];  // prefetch depth 2
        float a0 = xv0, a1 = 0.f, a2 = 0.f, a3 = 0.f;
        #pragma unroll
        for (int k = 0; k < HH; k += 4) {
            a0 = fmaf(w[k + 0], bcast(hv, k + 0), a0);
            a1 = fmaf(w[k + 1], bcast(hv, k + 1), a1);
            a2 = fmaf(w[k + 2], bcast(hv, k + 2), a2);
            a3 = fmaf(w[k + 3], bcast(hv, k + 3), a3);
        }
        hv = fast_tanh((a0 + a1) + (a2 + a3));
        hs[(t * BB + b) * HH + j] = hv;   // fire-and-forget
        xv0 = xv1;
        xv1 = xnext;
    }
}

// ---------------- device bodies for the mega-kernel phases -------------------

// bf16 MFMA GEMM tile (128x128), C = A @ W^T + bias; smem: As@0, Ws@10240
template<int K, bool RELU>
__device__ __forceinline__ void gemm_tile(char* smem,
                                          const float* __restrict__ A,
                                          const float* __restrict__ W,
                                          const float* __restrict__ bias,
                                          float* __restrict__ C, int N,
                                          int rowBase, int colBase) {
    short* As = (short*)smem;
    short* Ws = (short*)(smem + 10240);
    int tid = threadIdx.x;
    int wid = tid >> 6, lane = tid & 63;
    int col = lane & 15, quad = lane >> 4;

    f32x4 acc[2][8];
    #pragma unroll
    for (int nt = 0; nt < 8; nt++) {
        float bv = bias[colBase + nt * 16 + col];
        #pragma unroll
        for (int mt = 0; mt < 2; mt++) {
            acc[mt][nt][0] = bv; acc[mt][nt][1] = bv;
            acc[mt][nt][2] = bv; acc[mt][nt][3] = bv;
        }
    }

    int arow = tid >> 1, akb = (tid & 1) * 16;

    for (int kb = 0; kb < K; kb += 32) {
        {
            const float4* ap = (const float4*)(A + (size_t)(rowBase + arow) * K + kb + akb);
            float4 v0 = ap[0], v1 = ap[1], v2 = ap[2], v3 = ap[3];
            short t0[8], t1[8];
            t0[0]=f2bf(v0.x); t0[1]=f2bf(v0.y); t0[2]=f2bf(v0.z); t0[3]=f2bf(v0.w);
            t0[4]=f2bf(v1.x); t0[5]=f2bf(v1.y); t0[6]=f2bf(v1.z); t0[7]=f2bf(v1.w);
            t1[0]=f2bf(v2.x); t1[1]=f2bf(v2.y); t1[2]=f2bf(v2.z); t1[3]=f2bf(v2.w);
            t1[4]=f2bf(v3.x); t1[5]=f2bf(v3.y); t1[6]=f2bf(v3.z); t1[7]=f2bf(v3.w);
            *(int4*)&As[arow * 40 + akb]     = *(int4*)t0;
            *(int4*)&As[arow * 40 + akb + 8] = *(int4*)t1;
        }
        {
            const float4* wp = (const float4*)(W + (size_t)(colBase + arow) * K + kb + akb);
            float4 v0 = wp[0], v1 = wp[1], v2 = wp[2], v3 = wp[3];
            short t0[8], t1[8];
            t0[0]=f2bf(v0.x); t0[1]=f2bf(v0.y); t0[2]=f2bf(v0.z); t0[3]=f2bf(v0.w);
            t0[4]=f2bf(v1.x); t0[5]=f2bf(v1.y); t0[6]=f2bf(v1.z); t0[7]=f2bf(v1.w);
            t1[0]=f2bf(v2.x); t1[1]=f2bf(v2.y); t1[2]=f2bf(v2.z); t1[3]=f2bf(v2.w);
            t1[4]=f2bf(v3.x); t1[5]=f2bf(v3.y); t1[6]=f2bf(v3.z); t1[7]=f2bf(v3.w);
            *(int4*)&Ws[arow * 40 + akb]     = *(int4*)t0;
            *(int4*)&Ws[arow * 40 + akb + 8] = *(int4*)t1;
        }
        __syncthreads();

        bf16x8 af[2], wf[8];
        #pragma unroll
        for (int mt = 0; mt < 2; mt++)
            af[mt] = *(const bf16x8*)&As[(wid * 32 + mt * 16 + col) * 40 + quad * 8];
        #pragma unroll
        for (int nt = 0; nt < 8; nt++)
            wf[nt] = *(const bf16x8*)&Ws[(nt * 16 + col) * 40 + quad * 8];
        #pragma unroll
        for (int mt = 0; mt < 2; mt++)
            #pragma unroll
            for (int nt = 0; nt < 8; nt++)
                acc[mt][nt] = __builtin_amdgcn_mfma_f32_16x16x32_bf16(af[mt], wf[nt], acc[mt][nt], 0, 0, 0);
        __syncthreads();
    }

    #pragma unroll
    for (int mt = 0; mt < 2; mt++) {
        #pragma unroll
        for (int r = 0; r < 4; r++) {
            int m = rowBase + wid * 32 + mt * 16 + quad * 4 + r;
            float* crow = C + (size_t)m * N + colBase;
            #pragma unroll
            for (int nt = 0; nt < 8; nt++) {
                float v = acc[mt][nt][r];
                if (RELU) v = fmaxf(v, 0.f);
                crow[nt * 16 + col] = v;
            }
        }
    }
}

// GEMM tile (128x128, N=DD) with fused LayerNorm(s)
template<int K, int NLN>
__device__ __forceinline__ void gemm_ln_tile(char* smem,
                                             const float* __restrict__ A,
                                             const float* __restrict__ W,
                                             const float* __restrict__ bias,
                                             const float* __restrict__ res1,
                                             const float* __restrict__ g1v,
                                             const float* __restrict__ be1v,
                                             const float* __restrict__ res2,
                                             const float* __restrict__ g2v,
                                             const float* __restrict__ be2v,
                                             float* __restrict__ out, int rowBase) {
    short* As = (short*)smem;
    short* Ws = (short*)(smem + 10240);
    int tid = threadIdx.x;
    int wid = tid >> 6, lane = tid & 63;
    int col = lane & 15, quad = lane >> 4;

    f32x4 acc[2][8];
    #pragma unroll
    for (int nt = 0; nt < 8; nt++) {
        float bv = bias[nt * 16 + col];
        #pragma unroll
        for (int mt = 0; mt < 2; mt++) {
            acc[mt][nt][0] = bv; acc[mt][nt][1] = bv;
            acc[mt][nt][2] = bv; acc[mt][nt][3] = bv;
        }
    }

    int arow = tid >> 1, akb = (tid & 1) * 16;

    for (int kb = 0; kb < K; kb += 32) {
        {
            const float4* ap = (const float4*)(A + (size_t)(rowBase + arow) * K + kb + akb);
            float4 v0 = ap[0], v1 = ap[1], v2 = ap[2], v3 = ap[3];
            short t0[8], t1[8];
            t0[0]=f2bf(v0.x); t0[1]=f2bf(v0.y); t0[2]=f2bf(v0.z); t0[3]=f2bf(v0.w);
            t0[4]=f2bf(v1.x); t0[5]=f2bf(v1.y); t0[6]=f2bf(v1.z); t0[7]=f2bf(v1.w);
            t1[0]=f2bf(v2.x); t1[1]=f2bf(v2.y); t1[2]=f2bf(v2.z); t1[3]=f2bf(v2.w);
            t1[4]=f2bf(v3.x); t1[5]=f2bf(v3.y); t1[6]=f2bf(v3.z); t1[7]=f2bf(v3.w);
            *(int4*)&As[arow * 40 + akb]     = *(int4*)t0;
            *(int4*)&As[arow * 40 + akb + 8] = *(int4*)t1;
        }
        {
            const float4* wp = (const float4*)(W + (size_t)arow * K + kb + akb);
            float4 v0 = wp[0], v1 = wp[1], v2 = wp[2], v3 = wp[3];
            short t0[8], t1[8];
            t0[0]=f2bf(v0.x); t0[1]=f2bf(v0.y); t0[2]=f2bf(v0.z); t0[3]=f2bf(v0.w);
            t0[4]=f2bf(v1.x); t0[5]=f2bf(v1.y); t0[6]=f2bf(v1.z); t0[7]=f2bf(v1.w);
            t1[0]=f2bf(v2.x); t1[1]=f2bf(v2.y); t1[2]=f2bf(v2.z); t1[3]=f2bf(v2.w);
            t1[4]=f2bf(v3.x); t1[5]=f2bf(v3.y); t1[6]=f2bf(v3.z); t1[7]=f2bf(v3.w);
            *(int4*)&Ws[arow * 40 + akb]     = *(int4*)t0;
            *(int4*)&Ws[arow * 40 + akb + 8] = *(int4*)t1;
        }
        __syncthreads();

        bf16x8 af[2], wf[8];
        #pragma unroll
        for (int mt = 0; mt < 2; mt++)
            af[mt] = *(const bf16x8*)&As[(wid * 32 + mt * 16 + col) * 40 + quad * 8];
        #pragma unroll
        for (int nt = 0; nt < 8; nt++)
            wf[nt] = *(const bf16x8*)&Ws[(nt * 16 + col) * 40 + quad * 8];
        #pragma unroll
        for (int mt = 0; mt < 2; mt++)
            #pragma unroll
            for (int nt = 0; nt < 8; nt++)
                acc[mt][nt] = __builtin_amdgcn_mfma_f32_16x16x32_bf16(af[mt], wf[nt], acc[mt][nt], 0, 0, 0);
        __syncthreads();
    }

    float ga[8], ba[8], gb[8], bb[8];
    #pragma unroll
    for (int nt = 0; nt < 8; nt++) {
        ga[nt] = g1v[nt * 16 + col]; ba[nt] = be1v[nt * 16 + col];
        if (NLN == 2) { gb[nt] = g2v[nt * 16 + col]; bb[nt] = be2v[nt * 16 + col]; }
    }

    #pragma unroll
    for (int mt = 0; mt < 2; mt++) {
        #pragma unroll
        for (int r = 0; r < 4; r++) {
            int m = rowBase + wid * 32 + mt * 16 + quad * 4 + r;
            const float* rr1 = res1 + (size_t)m * DD;
            float v[8];
            float s = 0.f;
            #pragma unroll
            for (int nt = 0; nt < 8; nt++) {
                v[nt] = acc[mt][nt][r] + rr1[nt * 16 + col];
                s += v[nt];
            }
            #pragma unroll
            for (int off = 1; off < 16; off <<= 1) s += __shfl_xor(s, off, 64);
            float mu = s * (1.0f / 128.0f);
            float vs = 0.f;
            #pragma unroll
            for (int nt = 0; nt < 8; nt++) { v[nt] -= mu; vs += v[nt] * v[nt]; }
            #pragma unroll
            for (int off = 1; off < 16; off <<= 1) vs += __shfl_xor(vs, off, 64);
            float rstd = rsqrtf(vs * (1.0f / 128.0f) + 1e-5f);
            #pragma unroll
            for (int nt = 0; nt < 8; nt++) v[nt] = v[nt] * rstd * ga[nt] + ba[nt];

            if (NLN == 2) {
                const float* rr2 = res2 + (size_t)m * DD;
                float s2 = 0.f;
                #pragma unroll
                for (int nt = 0; nt < 8; nt++) {
                    v[nt] += rr2[nt * 16 + col];
                    s2 += v[nt];
                }
                #pragma unroll
                for (int off = 1; off < 16; off <<= 1) s2 += __shfl_xor(s2, off, 64);
                float mu2 = s2 * (1.0f / 128.0f);
                float vs2 = 0.f;
                #pragma unroll
                for (int nt = 0; nt < 8; nt++) { v[nt] -= mu2; vs2 += v[nt] * v[nt]; }
                #pragma unroll
                for (int off = 1; off < 16; off <<= 1) vs2 += __shfl_xor(vs2, off, 64);
                float rstd2 = rsqrtf(vs2 * (1.0f / 128.0f) + 1e-5f);
                #pragma unroll
                for (int nt = 0; nt < 8; nt++) v[nt] = v[nt] * rstd2 * gb[nt] + bb[nt];
            }

            float* orow = out + (size_t)m * DD;
            #pragma unroll
            for (int nt = 0; nt < 8; nt++) orow[nt * 16 + col] = v[nt];
        }
    }
}

// MFMA flash attention for one (b, head); smem: Vt@0 (16KB), Pb@16384 (16KB)
__device__ __forceinline__ void attn_one(char* smem, const float* __restrict__ qkv,
                                         float* __restrict__ ctx, int bh) {
    int b = bh >> 3, h = bh & 7;
    short (*Vt)[SS] = (short(*)[SS])smem;
    short* PbBase = (short*)(smem + 16384);
    int tid = threadIdx.x;

    for (int t = tid; t < SS; t += 256) {
        const float* base = qkv + (size_t)(t * BB + b) * 384 + h * 16;
        float4 v0 = *(const float4*)(base + 256);
        float4 v1 = *(const float4*)(base + 260);
        float4 v2 = *(const float4*)(base + 264);
        float4 v3 = *(const float4*)(base + 268);
        int u = t & 63;
        int pos = (t & ~63) | (((u & 15) << 2) | (u >> 4));
        Vt[0][pos]=f2bf(v0.x);  Vt[1][pos]=f2bf(v0.y);  Vt[2][pos]=f2bf(v0.z);  Vt[3][pos]=f2bf(v0.w);
        Vt[4][pos]=f2bf(v1.x);  Vt[5][pos]=f2bf(v1.y);  Vt[6][pos]=f2bf(v1.z);  Vt[7][pos]=f2bf(v1.w);
        Vt[8][pos]=f2bf(v2.x);  Vt[9][pos]=f2bf(v2.y);  Vt[10][pos]=f2bf(v2.z); Vt[11][pos]=f2bf(v2.w);
        Vt[12][pos]=f2bf(v3.x); Vt[13][pos]=f2bf(v3.y); Vt[14][pos]=f2bf(v3.z); Vt[15][pos]=f2bf(v3.w);
    }
    __syncthreads();

    int wid = tid >> 6, lane = tid & 63;
    int col = lane & 15, quad = lane >> 4;
    const float qscale = 0.25f * 1.44269504f;

    bf16x8 kf[32];
    #pragma unroll
    for (int kt = 0; kt < 32; kt++) {
        bf16x8 f = (bf16x8)(short)0;
        if (quad < 2) {
            const float* ksrc = qkv + (size_t)((kt * 16 + col) * BB + b) * 384 + 128 + h * 16 + quad * 8;
            float4 ka = *(const float4*)ksrc;
            float4 kb2 = *(const float4*)(ksrc + 4);
            f[0]=f2bf(ka.x);  f[1]=f2bf(ka.y);  f[2]=f2bf(ka.z);  f[3]=f2bf(ka.w);
            f[4]=f2bf(kb2.x); f[5]=f2bf(kb2.y); f[6]=f2bf(kb2.z); f[7]=f2bf(kb2.w);
        }
        kf[kt] = f;
    }

    for (int sub = 0; sub < 8; sub++) {
        int q0 = wid * 128 + sub * 16;

        bf16x8 qf = (bf16x8)(short)0;
        if (quad < 2) {
            const float* qsrc = qkv + (size_t)((q0 + col) * BB + b) * 384 + h * 16 + quad * 8;
            float4 qa = *(const float4*)qsrc;
            float4 qb = *(const float4*)(qsrc + 4);
            qf[0]=f2bf(qa.x*qscale); qf[1]=f2bf(qa.y*qscale);
            qf[2]=f2bf(qa.z*qscale); qf[3]=f2bf(qa.w*qscale);
            qf[4]=f2bf(qb.x*qscale); qf[5]=f2bf(qb.y*qscale);
            qf[6]=f2bf(qb.z*qscale); qf[7]=f2bf(qb.w*qscale);
        }

        float l0 = 0.f, l1 = 0.f, l2 = 0.f, l3 = 0.f;
        f32x4 O = {0.f, 0.f, 0.f, 0.f};
        #pragma unroll
        for (int c = 0; c < 8; c++) {
            short* pbuf = PbBase + (wid * 2 + (c & 1)) * 1024;
            float p[4][4];
            #pragma unroll
            for (int kk = 0; kk < 4; kk++) {
                f32x4 z = {0.f, 0.f, 0.f, 0.f};
                f32x4 S = __builtin_amdgcn_mfma_f32_16x16x32_bf16(qf, kf[c * 4 + kk], z, 0, 0, 0);
                p[kk][0] = exp2f(S[0]); p[kk][1] = exp2f(S[1]);
                p[kk][2] = exp2f(S[2]); p[kk][3] = exp2f(S[3]);
                l0 += p[kk][0]; l1 += p[kk][1]; l2 += p[kk][2]; l3 += p[kk][3];
            }
            #pragma unroll
            for (int r = 0; r < 4; r++) {
                unsigned w0 = (unsigned)(unsigned short)f2bf(p[0][r])
                            | ((unsigned)(unsigned short)f2bf(p[1][r]) << 16);
                unsigned w1 = (unsigned)(unsigned short)f2bf(p[2][r])
                            | ((unsigned)(unsigned short)f2bf(p[3][r]) << 16);
                *(uint2*)&pbuf[(4 * quad + r) * 64 + col * 4] = make_uint2(w0, w1);
            }
            #pragma unroll
            for (int half = 0; half < 2; half++) {
                int tb = c * 64 + half * 32;
                bf16x8 pf = *(const bf16x8*)&pbuf[col * 64 + half * 32 + quad * 8];
                bf16x8 vf = *(const bf16x8*)&Vt[col][tb + quad * 8];
                O = __builtin_amdgcn_mfma_f32_16x16x32_bf16(pf, vf, O, 0, 0, 0);
            }
        }

        float l[4] = {l0, l1, l2, l3};
        #pragma unroll
        for (int r = 0; r < 4; r++) {
            #pragma unroll
            for (int off = 1; off < 16; off <<= 1) l[r] += __shfl_xor(l[r], off, 64);
            float inv = __builtin_amdgcn_rcpf(l[r]);
            int q = q0 + 4 * quad + r;
            ctx[(size_t)(q * BB + b) * DD + h * 16 + col] = O[r] * inv;
        }
    }
}

// fused mean-pool + head for one batch b; smem: part@0 (1KB), pooled@1024
__device__ __forceinline__ void poolfinal_one(char* smem,
                                              const float* __restrict__ outln,
                                              const float* __restrict__ Wf,
                                              const float* __restrict__ bfv,
                                              float* __restrict__ out, int b) {
    float* part = (float*)smem;
    float* pooled = (float*)(smem + 1024);
    int tid = threadIdx.x;
    int d = tid & 127, half = tid >> 7;
    float s = 0.f;
    int s0 = half * 256;
    #pragma unroll 8
    for (int si = s0; si < s0 + 256; si++)
        s += outln[(size_t)(si * BB + b) * DD + d];
    part[tid] = s;
    __syncthreads();
    if (tid < 128) pooled[tid] = (part[tid] + part[tid + 128]) * (1.0f / SS);
    __syncthreads();
    if (tid < 32) {
        const float* wr = Wf + tid * DD;
        float acc = bfv[tid];
        #pragma unroll
        for (int k = 0; k < DD; k += 4) {
            float4 wv = *(const float4*)(wr + k);
            acc += pooled[k] * wv.x + pooled[k + 1] * wv.y
                 + pooled[k + 2] * wv.z + pooled[k + 3] * wv.w;
        }
        out[b * 32 + tid] = fast_tanh(acc);
    }
}

// ---------------- Mega-kernel: proj|qkv|attn|lnWo|ff1|ff2ln|pool ------------
// 256 blocks x 256 thr -> <=1 block/CU at any VGPR/LDS => all resident, no
// cooperative launch needed. 6 device-scope barriers replace 6 kernel gaps.
__global__ __launch_bounds__(256) void k_mega(
        const float* __restrict__ hsbuf,
        const float* __restrict__ Wp,   const float* __restrict__ bp,
        const float* __restrict__ Wqkv, const float* __restrict__ bqkv,
        const float* __restrict__ Wo,   const float* __restrict__ bo,
        const float* __restrict__ g1,   const float* __restrict__ be1,
        const float* __restrict__ W1,   const float* __restrict__ b1,
        const float* __restrict__ W2,   const float* __restrict__ b2,
        const float* __restrict__ g2,   const float* __restrict__ be2,
        const float* __restrict__ gn,   const float* __restrict__ bn,
        const float* __restrict__ Wf,   const float* __restrict__ bf,
        float* __restrict__ proj, float* __restrict__ qkv,
        float* __restrict__ ctx,  float* __restrict__ x1,
        float* __restrict__ ff1,  float* __restrict__ outln,
        float* __restrict__ out,  unsigned* __restrict__ ctr) {
    __shared__ __align__(16) char smem[32768];
    int bid = blockIdx.x;

    // P1: proj = hs @ Wp^T + bp      (M=32768 -> 256 tiles, N=128 -> 1)
    gemm_tile<64, false>(smem, hsbuf, Wp, bp, proj, 128, bid * 128, 0);
    gbar(&ctr[0], 256);

    // P2: qkv = proj @ Wqkv^T + bqkv (256 M-tiles x 3 N-tiles)
    for (int t = bid; t < 768; t += 256)
        gemm_tile<128, false>(smem, proj, Wqkv, bqkv, qkv, 384,
                              (t & 255) * 128, (t >> 8) * 128);
    gbar(&ctr[1], 256);

    // P3: attention (512 (b,h) pairs)
    for (int bh = bid; bh < 512; bh += 256) {
        attn_one(smem, qkv, ctx, bh);
        __syncthreads();
    }
    gbar(&ctr[2], 256);

    // P4: x1 = LN1(proj + ctx @ Wo^T + bo)
    gemm_ln_tile<128, 1>(smem, ctx, Wo, bo, proj, g1, be1,
                         nullptr, nullptr, nullptr, x1, bid * 128);
    gbar(&ctr[3], 256);

    // P5: ff1 = relu(x1 @ W1^T + b1) (256 M-tiles x 2 N-tiles)
    for (int t = bid; t < 512; t += 256)
        gemm_tile<128, true>(smem, x1, W1, b1, ff1, 256,
                             (t & 255) * 128, (t >> 8) * 128);
    gbar(&ctr[4], 256);

    // P6: outln = LN3(LN2(x1 + ff1 @ W2^T + b2) + proj)
    gemm_ln_tile<256, 2>(smem, ff1, W2, b2, x1, g2, be2,
                         proj, gn, bn, outln, bid * 128);
    gbar(&ctr[5], 256);

    // P7: pool + head (64 batches)
    if (bid < 64) poolfinal_one(smem, outln, Wf, bf, out, bid);
}

extern "C" void kernel_launch(void* const* d_in, const int* in_sizes, int n_in,
                              void* d_out, int out_size, void* d_ws, size_t ws_size,
                              hipStream_t stream) {
    const float* x    = (const float*)d_in[0];
    const float* W_ih = (const float*)d_in[1];
    const float* b_ih = (const float*)d_in[2];
    const float* W_hh = (const float*)d_in[3];
    const float* b_hh = (const float*)d_in[4];
    const float* Wp   = (const float*)d_in[5];
    const float* bp   = (const float*)d_in[6];
    const float* Wqkv = (const float*)d_in[7];
    const float* bqkv = (const float*)d_in[8];
    const float* Wo   = (const float*)d_in[9];
    const float* bo   = (const float*)d_in[10];
    const float* g1   = (const float*)d_in[11];
    const float* be1  = (const float*)d_in[12];
    const float* W1   = (const float*)d_in[13];
    const float* b1   = (const float*)d_in[14];
    const float* W2   = (const float*)d_in[15];
    const float* b2   = (const float*)d_in[16];
    const float* g2   = (const float*)d_in[17];
    const float* be2  = (const float*)d_in[18];
    const float* gn   = (const float*)d_in[19];
    const float* bn   = (const float*)d_in[20];
    const float* Wf   = (const float*)d_in[21];
    const float* bf   = (const float*)d_in[22];
    float* out = (float*)d_out;
    float* ws  = (float*)d_ws;

    // workspace layout (floats); regions reused once dead.
    float* proj   = ws + 0;          // 4M    [P1 .. end]
    float* qkv    = ws + 4194304;    // 12.6M [P2 .. P3]
    float* outln  = ws + 4194304;    // 4M    (reuses qkv, P6+)
    float* xw     = ws + 16777216;   // 2M    [xw .. rnn]
    float* hsbuf  = ws + 18874368;   // 2M    [rnn .. P1]
    float* ctx    = ws + 16777216;   // 4M    (reuses xw+hs, P3 .. P4)
    float* x1     = ws + 20971520;   // 4M    [P4 .. P6]
    float* ff1    = ws + 25165824;   // 8.4M  [P5 .. P6]
    unsigned* ctr = (unsigned*)(ws + 33554432);  // 6 barrier counters

    hipMemsetAsync(ctr, 0, 64, stream);
    k_xw<<<8192, 256, 0, stream>>>(x, W_ih, b_ih, b_hh, xw);
    k_rnn<<<64, 64, 0, stream>>>(xw, W_hh, hsbuf);
    k_mega<<<256, 256, 0, stream>>>(hsbuf, Wp, bp, Wqkv, bqkv, Wo, bo,
                                    g1, be1, W1, b1, W2, b2, g2, be2,
                                    gn, bn, Wf, bf,
                                    proj, qkv, ctx, x1, ff1, outln, out, ctr);
}

// Round 14
// 418.386 us; speedup vs baseline: 1.5261x; 1.5261x over previous
//
#include <hip/hip_runtime.h>
#include <hip/hip_bf16.h>

#define BB 64
#define SS 512
#define II 32
#define HH 64
#define DD 128
#define FF 256
#define NHEAD 8
#define HDIM 16
#define NTOK (SS*BB)   // 32768

typedef short bf16x8 __attribute__((ext_vector_type(8)));
typedef float f32x4  __attribute__((ext_vector_type(4)));

__device__ __forceinline__ float fast_tanh(float x) {
    float ax = fabsf(x);
    float e = __expf(-2.0f * ax);
    float r = (1.0f - e) * __builtin_amdgcn_rcpf(1.0f + e);
    return copysignf(r, x);
}

__device__ __forceinline__ float bcast(float v, int lane) {
    return __int_as_float(__builtin_amdgcn_readlane(__float_as_int(v), lane));
}

__device__ __forceinline__ short f2bf(float x) {
    unsigned u = __float_as_uint(x);
    return (short)((u + 0x7FFFu + ((u >> 16) & 1u)) >> 16);
}

// ---------------- Kernel 1: xw = x @ W_ih^T + b_ih + b_hh, layout (S,B,H) ----
__global__ __launch_bounds__(256) void k_xw(const float* __restrict__ x,
                                            const float* __restrict__ W_ih,
                                            const float* __restrict__ b_ih,
                                            const float* __restrict__ b_hh,
                                            float* __restrict__ xw) {
    int idx = blockIdx.x * 256 + threadIdx.x;  // over S*B*H = 2M
    int j  = idx & (HH - 1);
    int sb = idx >> 6;          // s*B + b
    int s  = sb >> 6;           // / B
    int b  = sb & (BB - 1);
    const float* xr = x + (b * SS + s) * II;
    const float* wr = W_ih + j * II;
    float acc = b_ih[j] + b_hh[j];
    #pragma unroll
    for (int k = 0; k < II; k += 4) {
        float4 xv = *(const float4*)(xr + k);
        float4 wv = *(const float4*)(wr + k);
        acc += xv.x * wv.x + xv.y * wv.y + xv.z * wv.z + xv.w * wv.w;
    }
    xw[idx] = acc;
}

// ---------------- Kernel 2: RNN recurrence, one block (1 wave) per batch ----
// FROZEN: byte-for-byte the R4/R5 body -- measured 134.5us FOUR times.
// Six variants all lost. DO NOT TOUCH without a structural idea.
__global__ __launch_bounds__(64, 1) void k_rnn(const float* __restrict__ xw,
                                               const float* __restrict__ W_hh,
                                               float* __restrict__ hs) {
    int b = blockIdx.x;
    int j = threadIdx.x;
    float w[HH];
    #pragma unroll
    for (int k = 0; k < HH; k++) w[k] = W_hh[j * HH + k];

    float hv = 0.0f;
    float xv0 = xw[(0 * BB + b) * HH + j];
    float xv1 = xw[(1 * BB + b) * HH + j];
    for (int t = 0; t < SS; t++) {
        int tn = (t < SS - 2) ? t + 2 : t;
        float xnext = xw[(tn * BB + b) * HH + j];  // prefetch depth 2
        float a0 = xv0, a1 = 0.f, a2 = 0.f, a3 = 0.f;
        #pragma unroll
        for (int k = 0; k < HH; k += 4) {
            a0 = fmaf(w[k + 0], bcast(hv, k + 0), a0);
            a1 = fmaf(w[k + 1], bcast(hv, k + 1), a1);
            a2 = fmaf(w[k + 2], bcast(hv, k + 2), a2);
            a3 = fmaf(w[k + 3], bcast(hv, k + 3), a3);
        }
        hv = fast_tanh((a0 + a1) + (a2 + a3));
        hs[(t * BB + b) * HH + j] = hv;   // fire-and-forget
        xv0 = xv1;
        xv1 = xnext;
    }
}

// ------ Kernel 3: bf16 MFMA GEMM, M=64 x N=128 tile, C = A @ W^T + bias -----
// R14 retile: M 128->64 halves LDS (15KB) and DOUBLES block count -- R13's
// mega-kernel profile proved the non-rnn side is occupancy/MLP-bound
// (1 block/CU = 4 waves/CU -> 806 GB/s on 309MB). 2-6 blocks/CU now.
// Wave wid owns rows [wid*16, wid*16+16); acc = 8 n-tiles (32 VGPR).
template<int K, bool RELU>
__global__ __launch_bounds__(256) void k_gemm_m64(const float* __restrict__ A,
                                                  const float* __restrict__ W,
                                                  const float* __restrict__ bias,
                                                  float* __restrict__ C, int N) {
    __shared__ short As[64 * 40];
    __shared__ short Ws[128 * 40];
    int tid = threadIdx.x;
    int wid = tid >> 6, lane = tid & 63;
    int col = lane & 15, quad = lane >> 4;
    int rowBase = blockIdx.x * 64, colBase = blockIdx.y * 128;

    f32x4 acc[8];
    #pragma unroll
    for (int nt = 0; nt < 8; nt++) {
        float bv = bias[colBase + nt * 16 + col];
        acc[nt][0] = bv; acc[nt][1] = bv; acc[nt][2] = bv; acc[nt][3] = bv;
    }

    int arow = tid >> 2, akb = (tid & 3) * 8;    // A: 8 floats each
    int wrow = tid >> 1, wkb = (tid & 1) * 16;   // W: 16 floats each

    for (int kb = 0; kb < K; kb += 32) {
        {
            const float4* ap = (const float4*)(A + (size_t)(rowBase + arow) * K + kb + akb);
            float4 v0 = ap[0], v1 = ap[1];
            short t0[8];
            t0[0]=f2bf(v0.x); t0[1]=f2bf(v0.y); t0[2]=f2bf(v0.z); t0[3]=f2bf(v0.w);
            t0[4]=f2bf(v1.x); t0[5]=f2bf(v1.y); t0[6]=f2bf(v1.z); t0[7]=f2bf(v1.w);
            *(int4*)&As[arow * 40 + akb] = *(int4*)t0;
        }
        {
            const float4* wp = (const float4*)(W + (size_t)(colBase + wrow) * K + kb + wkb);
            float4 v0 = wp[0], v1 = wp[1], v2 = wp[2], v3 = wp[3];
            short t0[8], t1[8];
            t0[0]=f2bf(v0.x); t0[1]=f2bf(v0.y); t0[2]=f2bf(v0.z); t0[3]=f2bf(v0.w);
            t0[4]=f2bf(v1.x); t0[5]=f2bf(v1.y); t0[6]=f2bf(v1.z); t0[7]=f2bf(v1.w);
            t1[0]=f2bf(v2.x); t1[1]=f2bf(v2.y); t1[2]=f2bf(v2.z); t1[3]=f2bf(v2.w);
            t1[4]=f2bf(v3.x); t1[5]=f2bf(v3.y); t1[6]=f2bf(v3.z); t1[7]=f2bf(v3.w);
            *(int4*)&Ws[wrow * 40 + wkb]     = *(int4*)t0;
            *(int4*)&Ws[wrow * 40 + wkb + 8] = *(int4*)t1;
        }
        __syncthreads();

        bf16x8 af = *(const bf16x8*)&As[(wid * 16 + col) * 40 + quad * 8];
        bf16x8 wf[8];
        #pragma unroll
        for (int nt = 0; nt < 8; nt++)
            wf[nt] = *(const bf16x8*)&Ws[(nt * 16 + col) * 40 + quad * 8];
        #pragma unroll
        for (int nt = 0; nt < 8; nt++)
            acc[nt] = __builtin_amdgcn_mfma_f32_16x16x32_bf16(af, wf[nt], acc[nt], 0, 0, 0);
        __syncthreads();
    }

    #pragma unroll
    for (int r = 0; r < 4; r++) {
        int m = rowBase + wid * 16 + quad * 4 + r;
        float* crow = C + (size_t)m * N + colBase;
        #pragma unroll
        for (int nt = 0; nt < 8; nt++) {
            float v = acc[nt][r];
            if (RELU) v = fmaxf(v, 0.f);
            crow[nt * 16 + col] = v;
        }
    }
}

// ------- GEMM (M=64 tile, N=DD) with fused LayerNorm(s) ---------------------
template<int K, int NLN>
__global__ __launch_bounds__(256) void k_gemm_ln_m64(const float* __restrict__ A,
                                                     const float* __restrict__ W,
                                                     const float* __restrict__ bias,
                                                     const float* __restrict__ res1,
                                                     const float* __restrict__ g1v,
                                                     const float* __restrict__ be1v,
                                                     const float* __restrict__ res2,
                                                     const float* __restrict__ g2v,
                                                     const float* __restrict__ be2v,
                                                     float* __restrict__ out) {
    __shared__ short As[64 * 40];
    __shared__ short Ws[128 * 40];
    int tid = threadIdx.x;
    int wid = tid >> 6, lane = tid & 63;
    int col = lane & 15, quad = lane >> 4;
    int rowBase = blockIdx.x * 64;

    f32x4 acc[8];
    #pragma unroll
    for (int nt = 0; nt < 8; nt++) {
        float bv = bias[nt * 16 + col];
        acc[nt][0] = bv; acc[nt][1] = bv; acc[nt][2] = bv; acc[nt][3] = bv;
    }

    int arow = tid >> 2, akb = (tid & 3) * 8;
    int wrow = tid >> 1, wkb = (tid & 1) * 16;

    for (int kb = 0; kb < K; kb += 32) {
        {
            const float4* ap = (const float4*)(A + (size_t)(rowBase + arow) * K + kb + akb);
            float4 v0 = ap[0], v1 = ap[1];
            short t0[8];
            t0[0]=f2bf(v0.x); t0[1]=f2bf(v0.y); t0[2]=f2bf(v0.z); t0[3]=f2bf(v0.w);
            t0[4]=f2bf(v1.x); t0[5]=f2bf(v1.y); t0[6]=f2bf(v1.z); t0[7]=f2bf(v1.w);
            *(int4*)&As[arow * 40 + akb] = *(int4*)t0;
        }
        {
            const float4* wp = (const float4*)(W + (size_t)wrow * K + kb + wkb);
            float4 v0 = wp[0], v1 = wp[1], v2 = wp[2], v3 = wp[3];
            short t0[8], t1[8];
            t0[0]=f2bf(v0.x); t0[1]=f2bf(v0.y); t0[2]=f2bf(v0.z); t0[3]=f2bf(v0.w);
            t0[4]=f2bf(v1.x); t0[5]=f2bf(v1.y); t0[6]=f2bf(v1.z); t0[7]=f2bf(v1.w);
            t1[0]=f2bf(v2.x); t1[1]=f2bf(v2.y); t1[2]=f2bf(v2.z); t1[3]=f2bf(v2.w);
            t1[4]=f2bf(v3.x); t1[5]=f2bf(v3.y); t1[6]=f2bf(v3.z); t1[7]=f2bf(v3.w);
            *(int4*)&Ws[wrow * 40 + wkb]     = *(int4*)t0;
            *(int4*)&Ws[wrow * 40 + wkb + 8] = *(int4*)t1;
        }
        __syncthreads();

        bf16x8 af = *(const bf16x8*)&As[(wid * 16 + col) * 40 + quad * 8];
        bf16x8 wf[8];
        #pragma unroll
        for (int nt = 0; nt < 8; nt++)
            wf[nt] = *(const bf16x8*)&Ws[(nt * 16 + col) * 40 + quad * 8];
        #pragma unroll
        for (int nt = 0; nt < 8; nt++)
            acc[nt] = __builtin_amdgcn_mfma_f32_16x16x32_bf16(af, wf[nt], acc[nt], 0, 0, 0);
        __syncthreads();
    }

    float ga[8], ba[8], gb[8], bb[8];
    #pragma unroll
    for (int nt = 0; nt < 8; nt++) {
        ga[nt] = g1v[nt * 16 + col]; ba[nt] = be1v[nt * 16 + col];
        if (NLN == 2) { gb[nt] = g2v[nt * 16 + col]; bb[nt] = be2v[nt * 16 + col]; }
    }

    #pragma unroll
    for (int r = 0; r < 4; r++) {
        int m = rowBase + wid * 16 + quad * 4 + r;
        const float* rr1 = res1 + (size_t)m * DD;
        float v[8];
        float s = 0.f;
        #pragma unroll
        for (int nt = 0; nt < 8; nt++) {
            v[nt] = acc[nt][r] + rr1[nt * 16 + col];
            s += v[nt];
        }
        #pragma unroll
        for (int off = 1; off < 16; off <<= 1) s += __shfl_xor(s, off, 64);
        float mu = s * (1.0f / 128.0f);
        float vs = 0.f;
        #pragma unroll
        for (int nt = 0; nt < 8; nt++) { v[nt] -= mu; vs += v[nt] * v[nt]; }
        #pragma unroll
        for (int off = 1; off < 16; off <<= 1) vs += __shfl_xor(vs, off, 64);
        float rstd = rsqrtf(vs * (1.0f / 128.0f) + 1e-5f);
        #pragma unroll
        for (int nt = 0; nt < 8; nt++) v[nt] = v[nt] * rstd * ga[nt] + ba[nt];

        if (NLN == 2) {
            const float* rr2 = res2 + (size_t)m * DD;
            float s2 = 0.f;
            #pragma unroll
            for (int nt = 0; nt < 8; nt++) {
                v[nt] += rr2[nt * 16 + col];
                s2 += v[nt];
            }
            #pragma unroll
            for (int off = 1; off < 16; off <<= 1) s2 += __shfl_xor(s2, off, 64);
            float mu2 = s2 * (1.0f / 128.0f);
            float vs2 = 0.f;
            #pragma unroll
            for (int nt = 0; nt < 8; nt++) { v[nt] -= mu2; vs2 += v[nt] * v[nt]; }
            #pragma unroll
            for (int off = 1; off < 16; off <<= 1) vs2 += __shfl_xor(vs2, off, 64);
            float rstd2 = rsqrtf(vs2 * (1.0f / 128.0f) + 1e-5f);
            #pragma unroll
            for (int nt = 0; nt < 8; nt++) v[nt] = v[nt] * rstd2 * gb[nt] + bb[nt];
        }

        float* orow = out + (size_t)m * DD;
        #pragma unroll
        for (int nt = 0; nt < 8; nt++) orow[nt * 16 + col] = v[nt];
    }
}

// ---------------- Kernel 4: MFMA flash attention (R12 form, unchanged) ------
__global__ __launch_bounds__(256, 2) void k_attn(const float* __restrict__ qkv,
                                                 float* __restrict__ ctx) {
    int bh = blockIdx.x;
    int b = bh >> 3, h = bh & 7;
    __shared__ short Vt[HDIM][SS];         // [d][k'] permuted within 64-chunks
    __shared__ short Pb[4][2][16 * 64];    // [wave][dbuf][qrow][64 k']
    int tid = threadIdx.x;

    for (int t = tid; t < SS; t += 256) {
        const float* base = qkv + (size_t)(t * BB + b) * 384 + h * 16;
        float4 v0 = *(const float4*)(base + 256);
        float4 v1 = *(const float4*)(base + 260);
        float4 v2 = *(const float4*)(base + 264);
        float4 v3 = *(const float4*)(base + 268);
        int u = t & 63;
        int pos = (t & ~63) | (((u & 15) << 2) | (u >> 4));
        Vt[0][pos]=f2bf(v0.x);  Vt[1][pos]=f2bf(v0.y);  Vt[2][pos]=f2bf(v0.z);  Vt[3][pos]=f2bf(v0.w);
        Vt[4][pos]=f2bf(v1.x);  Vt[5][pos]=f2bf(v1.y);  Vt[6][pos]=f2bf(v1.z);  Vt[7][pos]=f2bf(v1.w);
        Vt[8][pos]=f2bf(v2.x);  Vt[9][pos]=f2bf(v2.y);  Vt[10][pos]=f2bf(v2.z); Vt[11][pos]=f2bf(v2.w);
        Vt[12][pos]=f2bf(v3.x); Vt[13][pos]=f2bf(v3.y); Vt[14][pos]=f2bf(v3.z); Vt[15][pos]=f2bf(v3.w);
    }
    __syncthreads();

    int wid = tid >> 6, lane = tid & 63;
    int col = lane & 15, quad = lane >> 4;
    const float qscale = 0.25f * 1.44269504f;

    bf16x8 kf[32];
    #pragma unroll
    for (int kt = 0; kt < 32; kt++) {
        bf16x8 f = (bf16x8)(short)0;
        if (quad < 2) {
            const float* ksrc = qkv + (size_t)((kt * 16 + col) * BB + b) * 384 + 128 + h * 16 + quad * 8;
            float4 ka = *(const float4*)ksrc;
            float4 kb2 = *(const float4*)(ksrc + 4);
            f[0]=f2bf(ka.x);  f[1]=f2bf(ka.y);  f[2]=f2bf(ka.z);  f[3]=f2bf(ka.w);
            f[4]=f2bf(kb2.x); f[5]=f2bf(kb2.y); f[6]=f2bf(kb2.z); f[7]=f2bf(kb2.w);
        }
        kf[kt] = f;
    }

    for (int sub = 0; sub < 8; sub++) {
        int q0 = wid * 128 + sub * 16;

        bf16x8 qf = (bf16x8)(short)0;
        if (quad < 2) {
            const float* qsrc = qkv + (size_t)((q0 + col) * BB + b) * 384 + h * 16 + quad * 8;
            float4 qa = *(const float4*)qsrc;
            float4 qb = *(const float4*)(qsrc + 4);
            qf[0]=f2bf(qa.x*qscale); qf[1]=f2bf(qa.y*qscale);
            qf[2]=f2bf(qa.z*qscale); qf[3]=f2bf(qa.w*qscale);
            qf[4]=f2bf(qb.x*qscale); qf[5]=f2bf(qb.y*qscale);
            qf[6]=f2bf(qb.z*qscale); qf[7]=f2bf(qb.w*qscale);
        }

        float l0 = 0.f, l1 = 0.f, l2 = 0.f, l3 = 0.f;
        f32x4 O = {0.f, 0.f, 0.f, 0.f};
        #pragma unroll
        for (int c = 0; c < 8; c++) {
            short* pbuf = &Pb[wid][c & 1][0];
            float p[4][4];
            #pragma unroll
            for (int kk = 0; kk < 4; kk++) {
                f32x4 z = {0.f, 0.f, 0.f, 0.f};
                f32x4 S = __builtin_amdgcn_mfma_f32_16x16x32_bf16(qf, kf[c * 4 + kk], z, 0, 0, 0);
                p[kk][0] = exp2f(S[0]); p[kk][1] = exp2f(S[1]);
                p[kk][2] = exp2f(S[2]); p[kk][3] = exp2f(S[3]);
                l0 += p[kk][0]; l1 += p[kk][1]; l2 += p[kk][2]; l3 += p[kk][3];
            }
            #pragma unroll
            for (int r = 0; r < 4; r++) {
                unsigned w0 = (unsigned)(unsigned short)f2bf(p[0][r])
                            | ((unsigned)(unsigned short)f2bf(p[1][r]) << 16);
                unsigned w1 = (unsigned)(unsigned short)f2bf(p[2][r])
                            | ((unsigned)(unsigned short)f2bf(p[3][r]) << 16);
                *(uint2*)&pbuf[(4 * quad + r) * 64 + col * 4] = make_uint2(w0, w1);
            }
            #pragma unroll
            for (int half = 0; half < 2; half++) {
                int tb = c * 64 + half * 32;
                bf16x8 pf = *(const bf16x8*)&pbuf[col * 64 + half * 32 + quad * 8];
                bf16x8 vf = *(const bf16x8*)&Vt[col][tb + quad * 8];
                O = __builtin_amdgcn_mfma_f32_16x16x32_bf16(pf, vf, O, 0, 0, 0);
            }
        }

        float l[4] = {l0, l1, l2, l3};
        #pragma unroll
        for (int r = 0; r < 4; r++) {
            #pragma unroll
            for (int off = 1; off < 16; off <<= 1) l[r] += __shfl_xor(l[r], off, 64);
            float inv = __builtin_amdgcn_rcpf(l[r]);
            int q = q0 + 4 * quad + r;
            ctx[(size_t)(q * BB + b) * DD + h * 16 + col] = O[r] * inv;
        }
    }
}

// ---------------- Kernel 5: fused mean-pool + head ---------------------------
__global__ __launch_bounds__(256) void k_poolfinal(const float* __restrict__ outln,
                                                   const float* __restrict__ Wf,
                                                   const float* __restrict__ bfv,
                                                   float* __restrict__ out) {
    int b = blockIdx.x;
    int tid = threadIdx.x;
    __shared__ float part[256];
    __shared__ float pooled[128];
    int d = tid & 127, half = tid >> 7;
    float s = 0.f;
    int s0 = half * 256;
    #pragma unroll 8
    for (int si = s0; si < s0 + 256; si++)
        s += outln[(size_t)(si * BB + b) * DD + d];
    part[tid] = s;
    __syncthreads();
    if (tid < 128) pooled[tid] = (part[tid] + part[tid + 128]) * (1.0f / SS);
    __syncthreads();
    if (tid < 32) {
        const float* wr = Wf + tid * DD;
        float acc = bfv[tid];
        #pragma unroll
        for (int k = 0; k < DD; k += 4) {
            float4 wv = *(const float4*)(wr + k);
            acc += pooled[k] * wv.x + pooled[k + 1] * wv.y
                 + pooled[k + 2] * wv.z + pooled[k + 3] * wv.w;
        }
        out[b * 32 + tid] = fast_tanh(acc);
    }
}

extern "C" void kernel_launch(void* const* d_in, const int* in_sizes, int n_in,
                              void* d_out, int out_size, void* d_ws, size_t ws_size,
                              hipStream_t stream) {
    const float* x    = (const float*)d_in[0];
    const float* W_ih = (const float*)d_in[1];
    const float* b_ih = (const float*)d_in[2];
    const float* W_hh = (const float*)d_in[3];
    const float* b_hh = (const float*)d_in[4];
    const float* Wp   = (const float*)d_in[5];
    const float* bp   = (const float*)d_in[6];
    const float* Wqkv = (const float*)d_in[7];
    const float* bqkv = (const float*)d_in[8];
    const float* Wo   = (const float*)d_in[9];
    const float* bo   = (const float*)d_in[10];
    const float* g1   = (const float*)d_in[11];
    const float* be1  = (const float*)d_in[12];
    const float* W1   = (const float*)d_in[13];
    const float* b1   = (const float*)d_in[14];
    const float* W2   = (const float*)d_in[15];
    const float* b2   = (const float*)d_in[16];
    const float* g2   = (const float*)d_in[17];
    const float* be2  = (const float*)d_in[18];
    const float* gn   = (const float*)d_in[19];
    const float* bn   = (const float*)d_in[20];
    const float* Wf   = (const float*)d_in[21];
    const float* bf   = (const float*)d_in[22];
    float* out = (float*)d_out;
    float* ws  = (float*)d_ws;

    // workspace layout (floats); regions reused once dead.
    float* proj   = ws + 0;          // 4M    [phase 3 .. end]
    float* qkv    = ws + 4194304;    // 12.6M [phase 4 .. 5]
    float* outln  = ws + 4194304;    // 4M    (reuses qkv, phase 8+)
    float* xw     = ws + 16777216;   // 2M    [phase 1 .. 2]
    float* hsbuf  = ws + 18874368;   // 2M    [phase 2 .. 3]
    float* ctx    = ws + 16777216;   // 4M    (reuses xw+hs, phase 5 .. 6)
    float* x1     = ws + 20971520;   // 4M    [phase 6 .. 8]
    float* ff1    = ws + 25165824;   // 8.4M  [phase 7 .. 8]

    k_xw<<<8192, 256, 0, stream>>>(x, W_ih, b_ih, b_hh, xw);
    k_rnn<<<64, 64, 0, stream>>>(xw, W_hh, hsbuf);
    k_gemm_m64<64,  false><<<dim3(512, 1), 256, 0, stream>>>(hsbuf, Wp, bp, proj, 128);
    k_gemm_m64<128, false><<<dim3(512, 3), 256, 0, stream>>>(proj, Wqkv, bqkv, qkv, 384);
    k_attn<<<512, 256, 0, stream>>>(qkv, ctx);
    // x1 = LN1(proj + ctx@Wo^T + bo)
    k_gemm_ln_m64<128, 1><<<512, 256, 0, stream>>>(ctx, Wo, bo, proj, g1, be1,
                                                   nullptr, nullptr, nullptr, x1);
    k_gemm_m64<128, true ><<<dim3(512, 2), 256, 0, stream>>>(x1, W1, b1, ff1, 256);
    // outln = LN3( LN2(x1 + ff1@W2^T + b2) + proj )
    k_gemm_ln_m64<256, 2><<<512, 256, 0, stream>>>(ff1, W2, b2, x1, g2, be2,
                                                   proj, gn, bn, outln);
    k_poolfinal<<<64, 256, 0, stream>>>(outln, Wf, bf, out);
}

// Round 15
// 405.712 us; speedup vs baseline: 1.5738x; 1.0312x over previous
//
#include <hip/hip_runtime.h>
#include <hip/hip_bf16.h>

#define BB 64
#define SS 512
#define II 32
#define HH 64
#define DD 128
#define FF 256
#define NHEAD 8
#define HDIM 16
#define NTOK (SS*BB)   // 32768

typedef short bf16x8 __attribute__((ext_vector_type(8)));
typedef float f32x4  __attribute__((ext_vector_type(4)));

__device__ __forceinline__ float fast_tanh(float x) {
    float ax = fabsf(x);
    float e = __expf(-2.0f * ax);
    float r = (1.0f - e) * __builtin_amdgcn_rcpf(1.0f + e);
    return copysignf(r, x);
}

__device__ __forceinline__ float bcast(float v, int lane) {
    return __int_as_float(__builtin_amdgcn_readlane(__float_as_int(v), lane));
}

// fp32 -> bf16 bits, round-to-nearest-even
__device__ __forceinline__ short f2bf(float x) {
    unsigned u = __float_as_uint(x);
    return (short)((u + 0x7FFFu + ((u >> 16) & 1u)) >> 16);
}
__device__ __forceinline__ float bf2f(ushort u) {
    return __uint_as_float((unsigned)u << 16);
}

// ---------------- Kernel 0: weights fp32 -> bf16 (once per launch) ----------
// Wqkv K-rows (128..255) pre-scaled by 0.25*log2e so attention q/k loads are
// raw reinterprets (bqkv is zeros by construction, so its scaling is moot).
__global__ __launch_bounds__(256) void k_wcvt(const float* __restrict__ Wp,
                                              const float* __restrict__ Wqkv,
                                              const float* __restrict__ Wo,
                                              const float* __restrict__ W1,
                                              const float* __restrict__ W2,
                                              ushort* __restrict__ out) {
    int i = blockIdx.x * 256 + threadIdx.x;   // 139264 total
    float v;
    if (i < 8192) v = Wp[i];
    else if (i < 57344) {
        int e = i - 8192;
        v = Wqkv[e];
        int row = e >> 7;
        if (row >= 128 && row < 256) v *= 0.36067376f;  // 0.25 * log2(e)
    }
    else if (i < 73728) v = Wo[i - 57344];
    else if (i < 106496) v = W1[i - 73728];
    else v = W2[i - 106496];
    out[i] = (ushort)f2bf(v);
}

// ---------------- Kernel 1: xw = x @ W_ih^T + b_ih + b_hh, layout (S,B,H) ----
__global__ __launch_bounds__(256) void k_xw(const float* __restrict__ x,
                                            const float* __restrict__ W_ih,
                                            const float* __restrict__ b_ih,
                                            const float* __restrict__ b_hh,
                                            float* __restrict__ xw) {
    int idx = blockIdx.x * 256 + threadIdx.x;  // over S*B*H = 2M
    int j  = idx & (HH - 1);
    int sb = idx >> 6;          // s*B + b
    int s  = sb >> 6;           // / B
    int b  = sb & (BB - 1);
    const float* xr = x + (b * SS + s) * II;
    const float* wr = W_ih + j * II;
    float acc = b_ih[j] + b_hh[j];
    #pragma unroll
    for (int k = 0; k < II; k += 4) {
        float4 xv = *(const float4*)(xr + k);
        float4 wv = *(const float4*)(wr + k);
        acc += xv.x * wv.x + xv.y * wv.y + xv.z * wv.z + xv.w * wv.w;
    }
    xw[idx] = acc;
}

// ---------------- Kernel 2: RNN recurrence, one block (1 wave) per batch ----
// R4/R5 frozen body (134.5us x4). ONE deliberate change for the bf16
// pipeline: hs stored as bf16 (f2bf+store_short, off the critical path).
// If this regresses k_rnn, revert to fp32 store + separate cvt kernel.
__global__ __launch_bounds__(64, 1) void k_rnn(const float* __restrict__ xw,
                                               const float* __restrict__ W_hh,
                                               ushort* __restrict__ hs) {
    int b = blockIdx.x;
    int j = threadIdx.x;
    float w[HH];
    #pragma unroll
    for (int k = 0; k < HH; k++) w[k] = W_hh[j * HH + k];

    float hv = 0.0f;
    float xv0 = xw[(0 * BB + b) * HH + j];
    float xv1 = xw[(1 * BB + b) * HH + j];
    for (int t = 0; t < SS; t++) {
        int tn = (t < SS - 2) ? t + 2 : t;
        float xnext = xw[(tn * BB + b) * HH + j];  // prefetch depth 2
        float a0 = xv0, a1 = 0.f, a2 = 0.f, a3 = 0.f;
        #pragma unroll
        for (int k = 0; k < HH; k += 4) {
            a0 = fmaf(w[k + 0], bcast(hv, k + 0), a0);
            a1 = fmaf(w[k + 1], bcast(hv, k + 1), a1);
            a2 = fmaf(w[k + 2], bcast(hv, k + 2), a2);
            a3 = fmaf(w[k + 3], bcast(hv, k + 3), a3);
        }
        hv = fast_tanh((a0 + a1) + (a2 + a3));
        hs[(t * BB + b) * HH + j] = (ushort)f2bf(hv);   // fire-and-forget
        xv0 = xv1;
        xv1 = xnext;
    }
}

// ------ Kernel 3: bf16-in GEMM, M=64 x N=128 tile, C = A @ W^T + bias -------
// A and W are ALREADY bf16 in global -> staging is pure 16B copies (zero
// conversion VALU -- the R14 staging did ~50 cvt ops per k-step per thread).
template<int K, bool RELU, bool OUTBF>
__global__ __launch_bounds__(256) void k_gemm_m64b(const ushort* __restrict__ A,
                                                   const ushort* __restrict__ W,
                                                   const float* __restrict__ bias,
                                                   void* __restrict__ Cv, int N) {
    __shared__ short As[64 * 40];
    __shared__ short Ws[128 * 40];
    int tid = threadIdx.x;
    int wid = tid >> 6, lane = tid & 63;
    int col = lane & 15, quad = lane >> 4;
    int rowBase = blockIdx.x * 64, colBase = blockIdx.y * 128;

    f32x4 acc[8];
    #pragma unroll
    for (int nt = 0; nt < 8; nt++) {
        float bv = bias[colBase + nt * 16 + col];
        acc[nt][0] = bv; acc[nt][1] = bv; acc[nt][2] = bv; acc[nt][3] = bv;
    }

    int arow = tid >> 2, akc = (tid & 3) * 8;    // A: 8 bf16 (16B) each
    int wrow = tid >> 1, wkc = (tid & 1) * 16;   // W: 16 bf16 (32B) each

    for (int kb = 0; kb < K; kb += 32) {
        *(int4*)&As[arow * 40 + akc] =
            *(const int4*)(A + (size_t)(rowBase + arow) * K + kb + akc);
        {
            const int4* wp = (const int4*)(W + (size_t)(colBase + wrow) * K + kb + wkc);
            *(int4*)&Ws[wrow * 40 + wkc]     = wp[0];
            *(int4*)&Ws[wrow * 40 + wkc + 8] = wp[1];
        }
        __syncthreads();

        bf16x8 af = *(const bf16x8*)&As[(wid * 16 + col) * 40 + quad * 8];
        bf16x8 wf[8];
        #pragma unroll
        for (int nt = 0; nt < 8; nt++)
            wf[nt] = *(const bf16x8*)&Ws[(nt * 16 + col) * 40 + quad * 8];
        #pragma unroll
        for (int nt = 0; nt < 8; nt++)
            acc[nt] = __builtin_amdgcn_mfma_f32_16x16x32_bf16(af, wf[nt], acc[nt], 0, 0, 0);
        __syncthreads();
    }

    #pragma unroll
    for (int r = 0; r < 4; r++) {
        int m = rowBase + wid * 16 + quad * 4 + r;
        #pragma unroll
        for (int nt = 0; nt < 8; nt++) {
            float v = acc[nt][r];
            if (RELU) v = fmaxf(v, 0.f);
            if (OUTBF)
                ((ushort*)Cv)[(size_t)m * N + colBase + nt * 16 + col] = (ushort)f2bf(v);
            else
                ((float*)Cv)[(size_t)m * N + colBase + nt * 16 + col] = v;
        }
    }
}

// ------- GEMM (M=64 tile, N=DD) with fused LayerNorm(s), bf16 in ------------
template<int K, int NLN, bool OUTBF>
__global__ __launch_bounds__(256) void k_gemm_ln_m64b(const ushort* __restrict__ A,
                                                      const ushort* __restrict__ W,
                                                      const float* __restrict__ bias,
                                                      const ushort* __restrict__ res1,
                                                      const float* __restrict__ g1v,
                                                      const float* __restrict__ be1v,
                                                      const ushort* __restrict__ res2,
                                                      const float* __restrict__ g2v,
                                                      const float* __restrict__ be2v,
                                                      void* __restrict__ outv) {
    __shared__ short As[64 * 40];
    __shared__ short Ws[128 * 40];
    int tid = threadIdx.x;
    int wid = tid >> 6, lane = tid & 63;
    int col = lane & 15, quad = lane >> 4;
    int rowBase = blockIdx.x * 64;

    f32x4 acc[8];
    #pragma unroll
    for (int nt = 0; nt < 8; nt++) {
        float bv = bias[nt * 16 + col];
        acc[nt][0] = bv; acc[nt][1] = bv; acc[nt][2] = bv; acc[nt][3] = bv;
    }

    int arow = tid >> 2, akc = (tid & 3) * 8;
    int wrow = tid >> 1, wkc = (tid & 1) * 16;

    for (int kb = 0; kb < K; kb += 32) {
        *(int4*)&As[arow * 40 + akc] =
            *(const int4*)(A + (size_t)(rowBase + arow) * K + kb + akc);
        {
            const int4* wp = (const int4*)(W + (size_t)wrow * K + kb + wkc);
            *(int4*)&Ws[wrow * 40 + wkc]     = wp[0];
            *(int4*)&Ws[wrow * 40 + wkc + 8] = wp[1];
        }
        __syncthreads();

        bf16x8 af = *(const bf16x8*)&As[(wid * 16 + col) * 40 + quad * 8];
        bf16x8 wf[8];
        #pragma unroll
        for (int nt = 0; nt < 8; nt++)
            wf[nt] = *(const bf16x8*)&Ws[(nt * 16 + col) * 40 + quad * 8];
        #pragma unroll
        for (int nt = 0; nt < 8; nt++)
            acc[nt] = __builtin_amdgcn_mfma_f32_16x16x32_bf16(af, wf[nt], acc[nt], 0, 0, 0);
        __syncthreads();
    }

    float ga[8], ba[8], gb[8], bb[8];
    #pragma unroll
    for (int nt = 0; nt < 8; nt++) {
        ga[nt] = g1v[nt * 16 + col]; ba[nt] = be1v[nt * 16 + col];
        if (NLN == 2) { gb[nt] = g2v[nt * 16 + col]; bb[nt] = be2v[nt * 16 + col]; }
    }

    #pragma unroll
    for (int r = 0; r < 4; r++) {
        int m = rowBase + wid * 16 + quad * 4 + r;
        const ushort* rr1 = res1 + (size_t)m * DD;
        float v[8];
        float s = 0.f;
        #pragma unroll
        for (int nt = 0; nt < 8; nt++) {
            v[nt] = acc[nt][r] + bf2f(rr1[nt * 16 + col]);
            s += v[nt];
        }
        #pragma unroll
        for (int off = 1; off < 16; off <<= 1) s += __shfl_xor(s, off, 64);
        float mu = s * (1.0f / 128.0f);
        float vs = 0.f;
        #pragma unroll
        for (int nt = 0; nt < 8; nt++) { v[nt] -= mu; vs += v[nt] * v[nt]; }
        #pragma unroll
        for (int off = 1; off < 16; off <<= 1) vs += __shfl_xor(vs, off, 64);
        float rstd = rsqrtf(vs * (1.0f / 128.0f) + 1e-5f);
        #pragma unroll
        for (int nt = 0; nt < 8; nt++) v[nt] = v[nt] * rstd * ga[nt] + ba[nt];

        if (NLN == 2) {
            const ushort* rr2 = res2 + (size_t)m * DD;
            float s2 = 0.f;
            #pragma unroll
            for (int nt = 0; nt < 8; nt++) {
                v[nt] += bf2f(rr2[nt * 16 + col]);
                s2 += v[nt];
            }
            #pragma unroll
            for (int off = 1; off < 16; off <<= 1) s2 += __shfl_xor(s2, off, 64);
            float mu2 = s2 * (1.0f / 128.0f);
            float vs2 = 0.f;
            #pragma unroll
            for (int nt = 0; nt < 8; nt++) { v[nt] -= mu2; vs2 += v[nt] * v[nt]; }
            #pragma unroll
            for (int off = 1; off < 16; off <<= 1) vs2 += __shfl_xor(vs2, off, 64);
            float rstd2 = rsqrtf(vs2 * (1.0f / 128.0f) + 1e-5f);
            #pragma unroll
            for (int nt = 0; nt < 8; nt++) v[nt] = v[nt] * rstd2 * gb[nt] + bb[nt];
        }

        #pragma unroll
        for (int nt = 0; nt < 8; nt++) {
            if (OUTBF)
                ((ushort*)outv)[(size_t)m * DD + nt * 16 + col] = (ushort)f2bf(v[nt]);
            else
                ((float*)outv)[(size_t)m * DD + nt * 16 + col] = v[nt];
        }
    }
}

// ---------------- Kernel 4: MFMA flash attention, bf16 qkv ------------------
// qkv is bf16 with the score scale pre-folded into K (k_wcvt) -> q/k frag
// loads are raw 16B reinterprets; V staging is copy-only.
__global__ __launch_bounds__(256, 2) void k_attn(const ushort* __restrict__ qkv,
                                                 ushort* __restrict__ ctx) {
    int bh = blockIdx.x;
    int b = bh >> 3, h = bh & 7;
    __shared__ short Vt[HDIM][SS];         // [d][k'] permuted within 64-chunks
    __shared__ short Pb[4][2][16 * 64];    // [wave][dbuf][qrow][64 k']
    int tid = threadIdx.x;

    for (int t = tid; t < SS; t += 256) {
        const ushort* base = qkv + (size_t)(t * BB + b) * 384 + 256 + h * 16;
        int4 va = *(const int4*)base;
        int4 vb = *(const int4*)(base + 8);
        const ushort* pa = (const ushort*)&va;
        const ushort* pb = (const ushort*)&vb;
        int u = t & 63;
        int pos = (t & ~63) | (((u & 15) << 2) | (u >> 4));
        #pragma unroll
        for (int d = 0; d < 8; d++) {
            Vt[d][pos]     = pa[d];
            Vt[d + 8][pos] = pb[d];
        }
    }
    __syncthreads();

    int wid = tid >> 6, lane = tid & 63;
    int col = lane & 15, quad = lane >> 4;

    bf16x8 kf[32];
    #pragma unroll
    for (int kt = 0; kt < 32; kt++) {
        bf16x8 f = (bf16x8)(short)0;
        if (quad < 2)
            f = *(const bf16x8*)(qkv + (size_t)((kt * 16 + col) * BB + b) * 384
                                 + 128 + h * 16 + quad * 8);
        kf[kt] = f;
    }

    for (int sub = 0; sub < 8; sub++) {
        int q0 = wid * 128 + sub * 16;

        bf16x8 qf = (bf16x8)(short)0;
        if (quad < 2)
            qf = *(const bf16x8*)(qkv + (size_t)((q0 + col) * BB + b) * 384
                                  + h * 16 + quad * 8);

        float l0 = 0.f, l1 = 0.f, l2 = 0.f, l3 = 0.f;
        f32x4 O = {0.f, 0.f, 0.f, 0.f};
        #pragma unroll
        for (int c = 0; c < 8; c++) {
            short* pbuf = &Pb[wid][c & 1][0];
            float p[4][4];
            #pragma unroll
            for (int kk = 0; kk < 4; kk++) {
                f32x4 z = {0.f, 0.f, 0.f, 0.f};
                f32x4 S = __builtin_amdgcn_mfma_f32_16x16x32_bf16(qf, kf[c * 4 + kk], z, 0, 0, 0);
                p[kk][0] = exp2f(S[0]); p[kk][1] = exp2f(S[1]);
                p[kk][2] = exp2f(S[2]); p[kk][3] = exp2f(S[3]);
                l0 += p[kk][0]; l1 += p[kk][1]; l2 += p[kk][2]; l3 += p[kk][3];
            }
            #pragma unroll
            for (int r = 0; r < 4; r++) {
                unsigned w0 = (unsigned)(unsigned short)f2bf(p[0][r])
                            | ((unsigned)(unsigned short)f2bf(p[1][r]) << 16);
                unsigned w1 = (unsigned)(unsigned short)f2bf(p[2][r])
                            | ((unsigned)(unsigned short)f2bf(p[3][r]) << 16);
                *(uint2*)&pbuf[(4 * quad + r) * 64 + col * 4] = make_uint2(w0, w1);
            }
            #pragma unroll
            for (int half = 0; half < 2; half++) {
                int tb = c * 64 + half * 32;
                bf16x8 pf = *(const bf16x8*)&pbuf[col * 64 + half * 32 + quad * 8];
                bf16x8 vf = *(const bf16x8*)&Vt[col][tb + quad * 8];
                O = __builtin_amdgcn_mfma_f32_16x16x32_bf16(pf, vf, O, 0, 0, 0);
            }
        }

        float l[4] = {l0, l1, l2, l3};
        #pragma unroll
        for (int r = 0; r < 4; r++) {
            #pragma unroll
            for (int off = 1; off < 16; off <<= 1) l[r] += __shfl_xor(l[r], off, 64);
            float inv = __builtin_amdgcn_rcpf(l[r]);
            int q = q0 + 4 * quad + r;
            ctx[(size_t)(q * BB + b) * DD + h * 16 + col] = (ushort)f2bf(O[r] * inv);
        }
    }
}

// ---------------- Kernel 5: fused mean-pool + head (outln fp32) -------------
__global__ __launch_bounds__(256) void k_poolfinal(const float* __restrict__ outln,
                                                   const float* __restrict__ Wf,
                                                   const float* __restrict__ bfv,
                                                   float* __restrict__ out) {
    int b = blockIdx.x;
    int tid = threadIdx.x;
    __shared__ float part[256];
    __shared__ float pooled[128];
    int d = tid & 127, half = tid >> 7;
    float s = 0.f;
    int s0 = half * 256;
    #pragma unroll 8
    for (int si = s0; si < s0 + 256; si++)
        s += outln[(size_t)(si * BB + b) * DD + d];
    part[tid] = s;
    __syncthreads();
    if (tid < 128) pooled[tid] = (part[tid] + part[tid + 128]) * (1.0f / SS);
    __syncthreads();
    if (tid < 32) {
        const float* wr = Wf + tid * DD;
        float acc = bfv[tid];
        #pragma unroll
        for (int k = 0; k < DD; k += 4) {
            float4 wv = *(const float4*)(wr + k);
            acc += pooled[k] * wv.x + pooled[k + 1] * wv.y
                 + pooled[k + 2] * wv.z + pooled[k + 3] * wv.w;
        }
        out[b * 32 + tid] = fast_tanh(acc);
    }
}

extern "C" void kernel_launch(void* const* d_in, const int* in_sizes, int n_in,
                              void* d_out, int out_size, void* d_ws, size_t ws_size,
                              hipStream_t stream) {
    const float* x    = (const float*)d_in[0];
    const float* W_ih = (const float*)d_in[1];
    const float* b_ih = (const float*)d_in[2];
    const float* W_hh = (const float*)d_in[3];
    const float* b_hh = (const float*)d_in[4];
    const float* Wp   = (const float*)d_in[5];
    const float* bp   = (const float*)d_in[6];
    const float* Wqkv = (const float*)d_in[7];
    const float* bqkv = (const float*)d_in[8];
    const float* Wo   = (const float*)d_in[9];
    const float* bo   = (const float*)d_in[10];
    const float* g1   = (const float*)d_in[11];
    const float* be1  = (const float*)d_in[12];
    const float* W1   = (const float*)d_in[13];
    const float* b1   = (const float*)d_in[14];
    const float* W2   = (const float*)d_in[15];
    const float* b2   = (const float*)d_in[16];
    const float* g2   = (const float*)d_in[17];
    const float* be2  = (const float*)d_in[18];
    const float* gn   = (const float*)d_in[19];
    const float* bn   = (const float*)d_in[20];
    const float* Wf   = (const float*)d_in[21];
    const float* bf   = (const float*)d_in[22];
    float* out = (float*)d_out;
    char* wsb = (char*)d_ws;

    // workspace layout (bytes); bf16 intermediates throughout. ~92.3 MB.
    float*  xw    = (float*)(wsb);                      // 8MB   [xw .. rnn]
    ushort* hsb   = (ushort*)(wsb + (8u << 20));        // 4MB   [rnn .. proj]
    ushort* projb = (ushort*)(wsb + (12u << 20));       // 8MB   [proj .. end]
    ushort* qkvb  = (ushort*)(wsb + (20u << 20));       // 24MB  [qkv .. attn]
    ushort* ctxb  = (ushort*)(wsb + (44u << 20));       // 8MB   [attn .. Wo]
    ushort* x1b   = (ushort*)(wsb + (52u << 20));       // 8MB   [Wo .. ff2]
    ushort* ff1b  = (ushort*)(wsb + (60u << 20));       // 16MB  [ff1 .. ff2]
    float*  outln = (float*)(wsb + (76u << 20));        // 16MB  [ff2 .. pool]
    ushort* wbf   = (ushort*)(wsb + (92u << 20));       // 0.28MB weights
    ushort* Wp_bf   = wbf;
    ushort* Wqkv_bf = wbf + 8192;
    ushort* Wo_bf   = wbf + 57344;
    ushort* W1_bf   = wbf + 73728;
    ushort* W2_bf   = wbf + 106496;

    k_wcvt<<<544, 256, 0, stream>>>(Wp, Wqkv, Wo, W1, W2, wbf);
    k_xw<<<8192, 256, 0, stream>>>(x, W_ih, b_ih, b_hh, xw);
    k_rnn<<<64, 64, 0, stream>>>(xw, W_hh, hsb);
    k_gemm_m64b<64,  false, true><<<dim3(512, 1), 256, 0, stream>>>(hsb, Wp_bf, bp, projb, 128);
    k_gemm_m64b<128, false, true><<<dim3(512, 3), 256, 0, stream>>>(projb, Wqkv_bf, bqkv, qkvb, 384);
    k_attn<<<512, 256, 0, stream>>>(qkvb, ctxb);
    // x1 = LN1(proj + ctx@Wo^T + bo)
    k_gemm_ln_m64b<128, 1, true><<<512, 256, 0, stream>>>(ctxb, Wo_bf, bo, projb, g1, be1,
                                                          nullptr, nullptr, nullptr, x1b);
    k_gemm_m64b<128, true, true><<<dim3(512, 2), 256, 0, stream>>>(x1b, W1_bf, b1, ff1b, 256);
    // outln = LN3( LN2(x1 + ff1@W2^T + b2) + proj )   (fp32 out for pool)
    k_gemm_ln_m64b<256, 2, false><<<512, 256, 0, stream>>>(ff1b, W2_bf, b2, x1b, g2, be2,
                                                           projb, gn, bn, outln);
    k_poolfinal<<<64, 256, 0, stream>>>(outln, Wf, bf, out);
}

// Round 16
// 392.044 us; speedup vs baseline: 1.6287x; 1.0349x over previous
//
#include <hip/hip_runtime.h>
#include <hip/hip_bf16.h>

#define BB 64
#define SS 512
#define II 32
#define HH 64
#define DD 128
#define FF 256
#define NHEAD 8
#define HDIM 16
#define NTOK (SS*BB)   // 32768

typedef short bf16x8 __attribute__((ext_vector_type(8)));
typedef float f32x4  __attribute__((ext_vector_type(4)));

__device__ __forceinline__ float fast_tanh(float x) {
    float ax = fabsf(x);
    float e = __expf(-2.0f * ax);
    float r = (1.0f - e) * __builtin_amdgcn_rcpf(1.0f + e);
    return copysignf(r, x);
}

__device__ __forceinline__ float bcast(float v, int lane) {
    return __int_as_float(__builtin_amdgcn_readlane(__float_as_int(v), lane));
}

// fp32 -> bf16 bits, round-to-nearest-even
__device__ __forceinline__ short f2bf(float x) {
    unsigned u = __float_as_uint(x);
    return (short)((u + 0x7FFFu + ((u >> 16) & 1u)) >> 16);
}
__device__ __forceinline__ float bf2f(ushort u) {
    return __uint_as_float((unsigned)u << 16);
}

// ---------------- Kernel 1: xw (blocks < 8192) + weight-cvt (blocks >= 8192) -
// The two jobs are mutually independent and input-only -> one dispatch,
// one fewer serial launch gap. Wqkv K-rows pre-scaled by 0.25*log2e so
// attention q/k loads are raw reinterprets.
__global__ __launch_bounds__(256) void k_xw_wcvt(const float* __restrict__ x,
                                                 const float* __restrict__ W_ih,
                                                 const float* __restrict__ b_ih,
                                                 const float* __restrict__ b_hh,
                                                 float* __restrict__ xw,
                                                 const float* __restrict__ Wp,
                                                 const float* __restrict__ Wqkv,
                                                 const float* __restrict__ Wo,
                                                 const float* __restrict__ W1,
                                                 const float* __restrict__ W2,
                                                 ushort* __restrict__ wout) {
    if (blockIdx.x >= 8192) {
        int i = (blockIdx.x - 8192) * 256 + threadIdx.x;   // 139264 total
        float v;
        if (i < 8192) v = Wp[i];
        else if (i < 57344) {
            int e = i - 8192;
            v = Wqkv[e];
            int row = e >> 7;
            if (row >= 128 && row < 256) v *= 0.36067376f;  // 0.25 * log2(e)
        }
        else if (i < 73728) v = Wo[i - 57344];
        else if (i < 106496) v = W1[i - 73728];
        else v = W2[i - 106496];
        wout[i] = (ushort)f2bf(v);
        return;
    }
    int idx = blockIdx.x * 256 + threadIdx.x;  // over S*B*H = 2M
    int j  = idx & (HH - 1);
    int sb = idx >> 6;          // s*B + b
    int s  = sb >> 6;           // / B
    int b  = sb & (BB - 1);
    const float* xr = x + (b * SS + s) * II;
    const float* wr = W_ih + j * II;
    float acc = b_ih[j] + b_hh[j];
    #pragma unroll
    for (int k = 0; k < II; k += 4) {
        float4 xv = *(const float4*)(xr + k);
        float4 wv = *(const float4*)(wr + k);
        acc += xv.x * wv.x + xv.y * wv.y + xv.z * wv.z + xv.w * wv.w;
    }
    xw[idx] = acc;
}

// ---------------- Kernel 2: RNN recurrence, one block (1 wave) per batch ----
// FROZEN: byte-for-byte the R4/R5 body -- 134.5us x4; R15's bf16 store
// variant cost +10.5us (7th confirmation any in-loop change loses).
// fp32 hs; the bf16 conversion moved to proj's staging (bit-identical).
__global__ __launch_bounds__(64, 1) void k_rnn(const float* __restrict__ xw,
                                               const float* __restrict__ W_hh,
                                               float* __restrict__ hs) {
    int b = blockIdx.x;
    int j = threadIdx.x;
    float w[HH];
    #pragma unroll
    for (int k = 0; k < HH; k++) w[k] = W_hh[j * HH + k];

    float hv = 0.0f;
    float xv0 = xw[(0 * BB + b) * HH + j];
    float xv1 = xw[(1 * BB + b) * HH + j];
    for (int t = 0; t < SS; t++) {
        int tn = (t < SS - 2) ? t + 2 : t;
        float xnext = xw[(tn * BB + b) * HH + j];  // prefetch depth 2
        float a0 = xv0, a1 = 0.f, a2 = 0.f, a3 = 0.f;
        #pragma unroll
        for (int k = 0; k < HH; k += 4) {
            a0 = fmaf(w[k + 0], bcast(hv, k + 0), a0);
            a1 = fmaf(w[k + 1], bcast(hv, k + 1), a1);
            a2 = fmaf(w[k + 2], bcast(hv, k + 2), a2);
            a3 = fmaf(w[k + 3], bcast(hv, k + 3), a3);
        }
        hv = fast_tanh((a0 + a1) + (a2 + a3));
        hs[(t * BB + b) * HH + j] = hv;   // fire-and-forget
        xv0 = xv1;
        xv1 = xnext;
    }
}

// ------ Kernel 3a: GEMM with fp32 A (converted in staging), bf16 W ----------
// Only used for proj (A = fp32 hs). f2bf here produces values bit-identical
// to R15's rnn-side conversion.
template<int K, bool RELU>
__global__ __launch_bounds__(256) void k_gemm_m64fa(const float* __restrict__ A,
                                                    const ushort* __restrict__ W,
                                                    const float* __restrict__ bias,
                                                    ushort* __restrict__ C, int N) {
    __shared__ short As[64 * 40];
    __shared__ short Ws[128 * 40];
    int tid = threadIdx.x;
    int wid = tid >> 6, lane = tid & 63;
    int col = lane & 15, quad = lane >> 4;
    int rowBase = blockIdx.x * 64, colBase = blockIdx.y * 128;

    f32x4 acc[8];
    #pragma unroll
    for (int nt = 0; nt < 8; nt++) {
        float bv = bias[colBase + nt * 16 + col];
        acc[nt][0] = bv; acc[nt][1] = bv; acc[nt][2] = bv; acc[nt][3] = bv;
    }

    int arow = tid >> 2, akc = (tid & 3) * 8;
    int wrow = tid >> 1, wkc = (tid & 1) * 16;

    for (int kb = 0; kb < K; kb += 32) {
        {
            const float4* ap = (const float4*)(A + (size_t)(rowBase + arow) * K + kb + akc);
            float4 v0 = ap[0], v1 = ap[1];
            short t0[8];
            t0[0]=f2bf(v0.x); t0[1]=f2bf(v0.y); t0[2]=f2bf(v0.z); t0[3]=f2bf(v0.w);
            t0[4]=f2bf(v1.x); t0[5]=f2bf(v1.y); t0[6]=f2bf(v1.z); t0[7]=f2bf(v1.w);
            *(int4*)&As[arow * 40 + akc] = *(int4*)t0;
        }
        {
            const int4* wp = (const int4*)(W + (size_t)(colBase + wrow) * K + kb + wkc);
            *(int4*)&Ws[wrow * 40 + wkc]     = wp[0];
            *(int4*)&Ws[wrow * 40 + wkc + 8] = wp[1];
        }
        __syncthreads();

        bf16x8 af = *(const bf16x8*)&As[(wid * 16 + col) * 40 + quad * 8];
        bf16x8 wf[8];
        #pragma unroll
        for (int nt = 0; nt < 8; nt++)
            wf[nt] = *(const bf16x8*)&Ws[(nt * 16 + col) * 40 + quad * 8];
        #pragma unroll
        for (int nt = 0; nt < 8; nt++)
            acc[nt] = __builtin_amdgcn_mfma_f32_16x16x32_bf16(af, wf[nt], acc[nt], 0, 0, 0);
        __syncthreads();
    }

    #pragma unroll
    for (int r = 0; r < 4; r++) {
        int m = rowBase + wid * 16 + quad * 4 + r;
        #pragma unroll
        for (int nt = 0; nt < 8; nt++) {
            float v = acc[nt][r];
            if (RELU) v = fmaxf(v, 0.f);
            C[(size_t)m * N + colBase + nt * 16 + col] = (ushort)f2bf(v);
        }
    }
}

// ------ Kernel 3b: bf16-in GEMM, M=64 x N=128 tile (R15 form) ---------------
template<int K, bool RELU, bool OUTBF>
__global__ __launch_bounds__(256) void k_gemm_m64b(const ushort* __restrict__ A,
                                                   const ushort* __restrict__ W,
                                                   const float* __restrict__ bias,
                                                   void* __restrict__ Cv, int N) {
    __shared__ short As[64 * 40];
    __shared__ short Ws[128 * 40];
    int tid = threadIdx.x;
    int wid = tid >> 6, lane = tid & 63;
    int col = lane & 15, quad = lane >> 4;
    int rowBase = blockIdx.x * 64, colBase = blockIdx.y * 128;

    f32x4 acc[8];
    #pragma unroll
    for (int nt = 0; nt < 8; nt++) {
        float bv = bias[colBase + nt * 16 + col];
        acc[nt][0] = bv; acc[nt][1] = bv; acc[nt][2] = bv; acc[nt][3] = bv;
    }

    int arow = tid >> 2, akc = (tid & 3) * 8;    // A: 8 bf16 (16B) each
    int wrow = tid >> 1, wkc = (tid & 1) * 16;   // W: 16 bf16 (32B) each

    for (int kb = 0; kb < K; kb += 32) {
        *(int4*)&As[arow * 40 + akc] =
            *(const int4*)(A + (size_t)(rowBase + arow) * K + kb + akc);
        {
            const int4* wp = (const int4*)(W + (size_t)(colBase + wrow) * K + kb + wkc);
            *(int4*)&Ws[wrow * 40 + wkc]     = wp[0];
            *(int4*)&Ws[wrow * 40 + wkc + 8] = wp[1];
        }
        __syncthreads();

        bf16x8 af = *(const bf16x8*)&As[(wid * 16 + col) * 40 + quad * 8];
        bf16x8 wf[8];
        #pragma unroll
        for (int nt = 0; nt < 8; nt++)
            wf[nt] = *(const bf16x8*)&Ws[(nt * 16 + col) * 40 + quad * 8];
        #pragma unroll
        for (int nt = 0; nt < 8; nt++)
            acc[nt] = __builtin_amdgcn_mfma_f32_16x16x32_bf16(af, wf[nt], acc[nt], 0, 0, 0);
        __syncthreads();
    }

    #pragma unroll
    for (int r = 0; r < 4; r++) {
        int m = rowBase + wid * 16 + quad * 4 + r;
        #pragma unroll
        for (int nt = 0; nt < 8; nt++) {
            float v = acc[nt][r];
            if (RELU) v = fmaxf(v, 0.f);
            if (OUTBF)
                ((ushort*)Cv)[(size_t)m * N + colBase + nt * 16 + col] = (ushort)f2bf(v);
            else
                ((float*)Cv)[(size_t)m * N + colBase + nt * 16 + col] = v;
        }
    }
}

// ------- GEMM (M=64 tile, N=DD) with fused LayerNorm(s), bf16 in ------------
template<int K, int NLN, bool OUTBF>
__global__ __launch_bounds__(256) void k_gemm_ln_m64b(const ushort* __restrict__ A,
                                                      const ushort* __restrict__ W,
                                                      const float* __restrict__ bias,
                                                      const ushort* __restrict__ res1,
                                                      const float* __restrict__ g1v,
                                                      const float* __restrict__ be1v,
                                                      const ushort* __restrict__ res2,
                                                      const float* __restrict__ g2v,
                                                      const float* __restrict__ be2v,
                                                      void* __restrict__ outv) {
    __shared__ short As[64 * 40];
    __shared__ short Ws[128 * 40];
    int tid = threadIdx.x;
    int wid = tid >> 6, lane = tid & 63;
    int col = lane & 15, quad = lane >> 4;
    int rowBase = blockIdx.x * 64;

    f32x4 acc[8];
    #pragma unroll
    for (int nt = 0; nt < 8; nt++) {
        float bv = bias[nt * 16 + col];
        acc[nt][0] = bv; acc[nt][1] = bv; acc[nt][2] = bv; acc[nt][3] = bv;
    }

    int arow = tid >> 2, akc = (tid & 3) * 8;
    int wrow = tid >> 1, wkc = (tid & 1) * 16;

    for (int kb = 0; kb < K; kb += 32) {
        *(int4*)&As[arow * 40 + akc] =
            *(const int4*)(A + (size_t)(rowBase + arow) * K + kb + akc);
        {
            const int4* wp = (const int4*)(W + (size_t)wrow * K + kb + wkc);
            *(int4*)&Ws[wrow * 40 + wkc]     = wp[0];
            *(int4*)&Ws[wrow * 40 + wkc + 8] = wp[1];
        }
        __syncthreads();

        bf16x8 af = *(const bf16x8*)&As[(wid * 16 + col) * 40 + quad * 8];
        bf16x8 wf[8];
        #pragma unroll
        for (int nt = 0; nt < 8; nt++)
            wf[nt] = *(const bf16x8*)&Ws[(nt * 16 + col) * 40 + quad * 8];
        #pragma unroll
        for (int nt = 0; nt < 8; nt++)
            acc[nt] = __builtin_amdgcn_mfma_f32_16x16x32_bf16(af, wf[nt], acc[nt], 0, 0, 0);
        __syncthreads();
    }

    float ga[8], ba[8], gb[8], bb[8];
    #pragma unroll
    for (int nt = 0; nt < 8; nt++) {
        ga[nt] = g1v[nt * 16 + col]; ba[nt] = be1v[nt * 16 + col];
        if (NLN == 2) { gb[nt] = g2v[nt * 16 + col]; bb[nt] = be2v[nt * 16 + col]; }
    }

    #pragma unroll
    for (int r = 0; r < 4; r++) {
        int m = rowBase + wid * 16 + quad * 4 + r;
        const ushort* rr1 = res1 + (size_t)m * DD;
        float v[8];
        float s = 0.f;
        #pragma unroll
        for (int nt = 0; nt < 8; nt++) {
            v[nt] = acc[nt][r] + bf2f(rr1[nt * 16 + col]);
            s += v[nt];
        }
        #pragma unroll
        for (int off = 1; off < 16; off <<= 1) s += __shfl_xor(s, off, 64);
        float mu = s * (1.0f / 128.0f);
        float vs = 0.f;
        #pragma unroll
        for (int nt = 0; nt < 8; nt++) { v[nt] -= mu; vs += v[nt] * v[nt]; }
        #pragma unroll
        for (int off = 1; off < 16; off <<= 1) vs += __shfl_xor(vs, off, 64);
        float rstd = rsqrtf(vs * (1.0f / 128.0f) + 1e-5f);
        #pragma unroll
        for (int nt = 0; nt < 8; nt++) v[nt] = v[nt] * rstd * ga[nt] + ba[nt];

        if (NLN == 2) {
            const ushort* rr2 = res2 + (size_t)m * DD;
            float s2 = 0.f;
            #pragma unroll
            for (int nt = 0; nt < 8; nt++) {
                v[nt] += bf2f(rr2[nt * 16 + col]);
                s2 += v[nt];
            }
            #pragma unroll
            for (int off = 1; off < 16; off <<= 1) s2 += __shfl_xor(s2, off, 64);
            float mu2 = s2 * (1.0f / 128.0f);
            float vs2 = 0.f;
            #pragma unroll
            for (int nt = 0; nt < 8; nt++) { v[nt] -= mu2; vs2 += v[nt] * v[nt]; }
            #pragma unroll
            for (int off = 1; off < 16; off <<= 1) vs2 += __shfl_xor(vs2, off, 64);
            float rstd2 = rsqrtf(vs2 * (1.0f / 128.0f) + 1e-5f);
            #pragma unroll
            for (int nt = 0; nt < 8; nt++) v[nt] = v[nt] * rstd2 * gb[nt] + bb[nt];
        }

        #pragma unroll
        for (int nt = 0; nt < 8; nt++) {
            if (OUTBF)
                ((ushort*)outv)[(size_t)m * DD + nt * 16 + col] = (ushort)f2bf(v[nt]);
            else
                ((float*)outv)[(size_t)m * DD + nt * 16 + col] = v[nt];
        }
    }
}

// ---------------- Kernel 4: MFMA flash attention, bf16 qkv (R15 form) -------
__global__ __launch_bounds__(256, 2) void k_attn(const ushort* __restrict__ qkv,
                                                 ushort* __restrict__ ctx) {
    int bh = blockIdx.x;
    int b = bh >> 3, h = bh & 7;
    __shared__ short Vt[HDIM][SS];         // [d][k'] permuted within 64-chunks
    __shared__ short Pb[4][2][16 * 64];    // [wave][dbuf][qrow][64 k']
    int tid = threadIdx.x;

    for (int t = tid; t < SS; t += 256) {
        const ushort* base = qkv + (size_t)(t * BB + b) * 384 + 256 + h * 16;
        int4 va = *(const int4*)base;
        int4 vb = *(const int4*)(base + 8);
        const ushort* pa = (const ushort*)&va;
        const ushort* pb = (const ushort*)&vb;
        int u = t & 63;
        int pos = (t & ~63) | (((u & 15) << 2) | (u >> 4));
        #pragma unroll
        for (int d = 0; d < 8; d++) {
            Vt[d][pos]     = pa[d];
            Vt[d + 8][pos] = pb[d];
        }
    }
    __syncthreads();

    int wid = tid >> 6, lane = tid & 63;
    int col = lane & 15, quad = lane >> 4;

    bf16x8 kf[32];
    #pragma unroll
    for (int kt = 0; kt < 32; kt++) {
        bf16x8 f = (bf16x8)(short)0;
        if (quad < 2)
            f = *(const bf16x8*)(qkv + (size_t)((kt * 16 + col) * BB + b) * 384
                                 + 128 + h * 16 + quad * 8);
        kf[kt] = f;
    }

    for (int sub = 0; sub < 8; sub++) {
        int q0 = wid * 128 + sub * 16;

        bf16x8 qf = (bf16x8)(short)0;
        if (quad < 2)
            qf = *(const bf16x8*)(qkv + (size_t)((q0 + col) * BB + b) * 384
                                  + h * 16 + quad * 8);

        float l0 = 0.f, l1 = 0.f, l2 = 0.f, l3 = 0.f;
        f32x4 O = {0.f, 0.f, 0.f, 0.f};
        #pragma unroll
        for (int c = 0; c < 8; c++) {
            short* pbuf = &Pb[wid][c & 1][0];
            float p[4][4];
            #pragma unroll
            for (int kk = 0; kk < 4; kk++) {
                f32x4 z = {0.f, 0.f, 0.f, 0.f};
                f32x4 S = __builtin_amdgcn_mfma_f32_16x16x32_bf16(qf, kf[c * 4 + kk], z, 0, 0, 0);
                p[kk][0] = exp2f(S[0]); p[kk][1] = exp2f(S[1]);
                p[kk][2] = exp2f(S[2]); p[kk][3] = exp2f(S[3]);
                l0 += p[kk][0]; l1 += p[kk][1]; l2 += p[kk][2]; l3 += p[kk][3];
            }
            #pragma unroll
            for (int r = 0; r < 4; r++) {
                unsigned w0 = (unsigned)(unsigned short)f2bf(p[0][r])
                            | ((unsigned)(unsigned short)f2bf(p[1][r]) << 16);
                unsigned w1 = (unsigned)(unsigned short)f2bf(p[2][r])
                            | ((unsigned)(unsigned short)f2bf(p[3][r]) << 16);
                *(uint2*)&pbuf[(4 * quad + r) * 64 + col * 4] = make_uint2(w0, w1);
            }
            #pragma unroll
            for (int half = 0; half < 2; half++) {
                int tb = c * 64 + half * 32;
                bf16x8 pf = *(const bf16x8*)&pbuf[col * 64 + half * 32 + quad * 8];
                bf16x8 vf = *(const bf16x8*)&Vt[col][tb + quad * 8];
                O = __builtin_amdgcn_mfma_f32_16x16x32_bf16(pf, vf, O, 0, 0, 0);
            }
        }

        float l[4] = {l0, l1, l2, l3};
        #pragma unroll
        for (int r = 0; r < 4; r++) {
            #pragma unroll
            for (int off = 1; off < 16; off <<= 1) l[r] += __shfl_xor(l[r], off, 64);
            float inv = __builtin_amdgcn_rcpf(l[r]);
            int q = q0 + 4 * quad + r;
            ctx[(size_t)(q * BB + b) * DD + h * 16 + col] = (ushort)f2bf(O[r] * inv);
        }
    }
}

// ---------------- Kernel 5: fused mean-pool + head (outln fp32) -------------
__global__ __launch_bounds__(256) void k_poolfinal(const float* __restrict__ outln,
                                                   const float* __restrict__ Wf,
                                                   const float* __restrict__ bfv,
                                                   float* __restrict__ out) {
    int b = blockIdx.x;
    int tid = threadIdx.x;
    __shared__ float part[256];
    __shared__ float pooled[128];
    int d = tid & 127, half = tid >> 7;
    float s = 0.f;
    int s0 = half * 256;
    #pragma unroll 8
    for (int si = s0; si < s0 + 256; si++)
        s += outln[(size_t)(si * BB + b) * DD + d];
    part[tid] = s;
    __syncthreads();
    if (tid < 128) pooled[tid] = (part[tid] + part[tid + 128]) * (1.0f / SS);
    __syncthreads();
    if (tid < 32) {
        const float* wr = Wf + tid * DD;
        float acc = bfv[tid];
        #pragma unroll
        for (int k = 0; k < DD; k += 4) {
            float4 wv = *(const float4*)(wr + k);
            acc += pooled[k] * wv.x + pooled[k + 1] * wv.y
                 + pooled[k + 2] * wv.z + pooled[k + 3] * wv.w;
        }
        out[b * 32 + tid] = fast_tanh(acc);
    }
}

extern "C" void kernel_launch(void* const* d_in, const int* in_sizes, int n_in,
                              void* d_out, int out_size, void* d_ws, size_t ws_size,
                              hipStream_t stream) {
    const float* x    = (const float*)d_in[0];
    const float* W_ih = (const float*)d_in[1];
    const float* b_ih = (const float*)d_in[2];
    const float* W_hh = (const float*)d_in[3];
    const float* b_hh = (const float*)d_in[4];
    const float* Wp   = (const float*)d_in[5];
    const float* bp   = (const float*)d_in[6];
    const float* Wqkv = (const float*)d_in[7];
    const float* bqkv = (const float*)d_in[8];
    const float* Wo   = (const float*)d_in[9];
    const float* bo   = (const float*)d_in[10];
    const float* g1   = (const float*)d_in[11];
    const float* be1  = (const float*)d_in[12];
    const float* W1   = (const float*)d_in[13];
    const float* b1   = (const float*)d_in[14];
    const float* W2   = (const float*)d_in[15];
    const float* b2   = (const float*)d_in[16];
    const float* g2   = (const float*)d_in[17];
    const float* be2  = (const float*)d_in[18];
    const float* gn   = (const float*)d_in[19];
    const float* bn   = (const float*)d_in[20];
    const float* Wf   = (const float*)d_in[21];
    const float* bf   = (const float*)d_in[22];
    float* out = (float*)d_out;
    char* wsb = (char*)d_ws;

    // workspace layout (bytes); bf16 intermediates. ~92.3 MB.
    float*  xw    = (float*)(wsb);                      // 8MB   [xw .. rnn]
    float*  hsf   = (float*)(wsb + (8u << 20));         // 8MB   [rnn .. proj]
    ushort* projb = (ushort*)(wsb + (16u << 20));       // 8MB   [proj .. end]
    ushort* qkvb  = (ushort*)(wsb + (24u << 20));       // 24MB  [qkv .. attn]
    ushort* ctxb  = (ushort*)(wsb + (48u << 20));       // 8MB   [attn .. Wo]
    ushort* x1b   = (ushort*)(wsb + (56u << 20));       // 8MB   [Wo .. ff2]
    ushort* ff1b  = (ushort*)(wsb + (64u << 20));       // 16MB  [ff1 .. ff2]
    float*  outln = (float*)(wsb + (80u << 20));        // 16MB  [ff2 .. pool]
    ushort* wbf   = (ushort*)(wsb + (96u << 20));       // 0.28MB weights
    ushort* Wp_bf   = wbf;
    ushort* Wqkv_bf = wbf + 8192;
    ushort* Wo_bf   = wbf + 57344;
    ushort* W1_bf   = wbf + 73728;
    ushort* W2_bf   = wbf + 106496;

    k_xw_wcvt<<<8736, 256, 0, stream>>>(x, W_ih, b_ih, b_hh, xw,
                                        Wp, Wqkv, Wo, W1, W2, wbf);
    k_rnn<<<64, 64, 0, stream>>>(xw, W_hh, hsf);
    k_gemm_m64fa<64, false><<<dim3(512, 1), 256, 0, stream>>>(hsf, Wp_bf, bp, projb, 128);
    k_gemm_m64b<128, false, true><<<dim3(512, 3), 256, 0, stream>>>(projb, Wqkv_bf, bqkv, qkvb, 384);
    k_attn<<<512, 256, 0, stream>>>(qkvb, ctxb);
    // x1 = LN1(proj + ctx@Wo^T + bo)
    k_gemm_ln_m64b<128, 1, true><<<512, 256, 0, stream>>>(ctxb, Wo_bf, bo, projb, g1, be1,
                                                          nullptr, nullptr, nullptr, x1b);
    k_gemm_m64b<128, true, true><<<dim3(512, 2), 256, 0, stream>>>(x1b, W1_bf, b1, ff1b, 256);
    // outln = LN3( LN2(x1 + ff1@W2^T + b2) + proj )   (fp32 out for pool)
    k_gemm_ln_m64b<256, 2, false><<<512, 256, 0, stream>>>(ff1b, W2_bf, b2, x1b, g2, be2,
                                                           projb, gn, bn, outln);
    k_poolfinal<<<64, 256, 0, stream>>>(outln, Wf, bf, out);
}